// Round 1
// 227.334 us; speedup vs baseline: 1.0776x; 1.0776x over previous
//
#include <hip/hip_runtime.h>

#define CH 16
#define NB 8

typedef unsigned short u16;
typedef unsigned int u32;
typedef __attribute__((ext_vector_type(8))) short s16x8;
typedef __attribute__((ext_vector_type(4))) float f32x4;

__device__ __forceinline__ float bflo(u32 u) { return __uint_as_float(u << 16); }
__device__ __forceinline__ float bfhi(u32 u) { return __uint_as_float(u & 0xffff0000u); }
__device__ __forceinline__ u32 bfrnd(float f) {
  u32 u = __float_as_uint(f);
  return (u + 0x7fffu + ((u >> 16) & 1u)) >> 16;
}
__device__ __forceinline__ u32 packbf(float lo, float hi) {
  return bfrnd(lo) | (bfrnd(hi) << 16);
}

// ---- Prep: build bf16 B-fragments for all 3 MFMA stages (once) ------------
__global__ __launch_bounds__(256) void bprep_kernel(
    const float* __restrict__ w_stg, u16* __restrict__ bpre)
{
  const int e = blockIdx.x * 256 + (int)threadIdx.x;
  if (e >= 3 * 7168) return;
  const int s = e / 7168, r0 = e % 7168;
  const int i = r0 >> 9;
  const int r = r0 & 511;
  const int l = r >> 3, j = r & 7;
  const int tap = 2 * i + (l >> 5);
  const int cin = ((l >> 4) & 1) * 8 + j;
  const int n = l & 15;
  const float* w = w_stg + s * 27 * 256;
  const float val = (tap < 27) ? w[(tap * 16 + cin) * 16 + n] : 0.f;
  bpre[s * 7168 + i * 512 + l * 8 + j] = (u16)bfrnd(val);
}

// ---- Stem via MFMA implicit GEMM, vector-gather rewrite -------------------
// K reordered as k' = (dz*5+dy)*8 + dx  (dx slots 5..7 -> zero weights), so
// each B-fragment (voxel taps) is 8 contiguous u16 of one tile row. 8
// shifted LDS copies (copy p = tile shifted by p u16, stride 2336B = 8 dw
// mod 32 -> bank-uniform) give 16B-aligned conflict-free ds_read_b128.
// Operands swapped vs old version: A = weights (m = out-ch, in regs),
// B = taps (n = voxel) -> C row = channel, col = voxel -> direct packed
// uint2 store, no lC LDS round-trip, no per-subtile barriers.
__global__ __launch_bounds__(256) void stem_mfma(
    const float* __restrict__ x, const int* __restrict__ mask,
    const float* __restrict__ wst, u16* __restrict__ yout,
    float* __restrict__ pool_sum, float* __restrict__ cnt)
{
  __shared__ u16 tl[144 * 24];      // linear halo tile, row stride 24 u16
  __shared__ u16 cp[8 * 1168];      // 8 shifted copies, stride 1168 u16

  const int b = blockIdx.y;
  // XCD swizzle: hw xcd = blockIdx.x % 8; give each xcd one z-slab (tb>>6)
  const int u = blockIdx.x;
  const int tb = ((u & 7) << 6) | (u >> 3);
  const int z0 = (tb >> 6) * 8;
  const int y0 = ((tb >> 3) & 7) * 8;
  const int x0 = (tb & 7) * 8;
  const int tid = threadIdx.x;

  if (tb == 0) {
    if (tid < 96) pool_sum[b * 96 + tid] = 0.f;
    else if (tid < 102) cnt[b * 6 + (tid - 96)] = 0.f;
  }

  const int lane = tid & 63;
  const int wv = tid >> 6;
  const int n = lane & 15;          // A row = out-ch ; B col = voxel
  const int quad = lane >> 4;
  const int vy = n >> 2, vx = n & 3;

  // ---- weight A-fragments: 7 MFMAs cover 28 tap-rows x 8 dx-slots ----
  s16x8 wf[7];
#pragma unroll
  for (int i = 0; i < 7; ++i) {
    const int r = i * 4 + quad;
#pragma unroll
    for (int j = 0; j < 8; ++j) {
      float v = 0.f;
      if (r < 25 && j < 5) v = wst[(r * 5 + j) * 16 + n];
      wf[i][j] = (short)bfrnd(v);
    }
  }

  // ---- phase 1: coalesced x*mask -> linear tile (bf16) ----
  for (int i = tid; i < 1728; i += 256) {
    const int row = i / 12;         // z*12 + y
    const int lx = i - row * 12;
    const int lz = row / 12;
    const int ly = row - lz * 12;
    const int gz = z0 + lz - 2, gy = y0 + ly - 2, gx = x0 + lx - 2;
    float v = 0.f;
    if ((unsigned)gz < 64u && (unsigned)gy < 64u && (unsigned)gx < 64u) {
      const int gi = ((b * 64 + gz) * 64 + gy) * 64 + gx;
      v = x[gi] * (float)mask[gi];
    }
    tl[row * 24 + lx] = (u16)bfrnd(v);
  }
  __syncthreads();

  // ---- phase 2: build 8 shifted copies; copy p row holds src x = p..p+7 ----
  if (tid < 144) {
    const uint4 a = *(const uint4*)&tl[tid * 24];       // x0..x7
    const uint2 bq = *(const uint2*)&tl[tid * 24 + 8];  // x8..x11
    u32 c[7];
    c[0] = a.x; c[1] = a.y; c[2] = a.z; c[3] = a.w;
    c[4] = bq.x; c[5] = bq.y; c[6] = 0u;
    u32 d[7];
#pragma unroll
    for (int k = 0; k < 6; ++k) d[k] = (c[k] >> 16) | (c[k + 1] << 16);
    d[6] = c[6] >> 16;
    uint4* dst = (uint4*)&cp[tid * 8];                  // +p*146 uint4/copy
    dst[0 * 146] = make_uint4(c[0], c[1], c[2], c[3]);
    dst[1 * 146] = make_uint4(d[0], d[1], d[2], d[3]);
    dst[2 * 146] = make_uint4(c[1], c[2], c[3], c[4]);
    dst[3 * 146] = make_uint4(d[1], d[2], d[3], d[4]);
    dst[4 * 146] = make_uint4(c[2], c[3], c[4], c[5]);
    dst[5 * 146] = make_uint4(d[2], d[3], d[4], d[5]);
    dst[6 * 146] = make_uint4(c[3], c[4], c[5], c[6]);
    dst[7 * 146] = make_uint4(d[3], d[4], d[5], d[6]);
  }
  __syncthreads();

  // per-quad tap-row offsets (u16 units); r>=25 clamped to row 0 (zero wt)
  int doff[7];
#pragma unroll
  for (int i = 0; i < 7; ++i) {
    const int r = i * 4 + quad;
    doff[i] = (r < 25) ? ((r / 5) * 12 + (r % 5)) * 8 : 0;
  }

  for (int s = 0; s < 8; ++s) {
    const int sz = (s >> 2) * 4, sy = ((s >> 1) & 1) * 4, sx = (s & 1) * 4;
    const int base =
        (sx + vx) * 1168 + (((sz + wv) * 12) + (sy + vy)) * 8;
    f32x4 acc = {0.f, 0.f, 0.f, 0.f};
#pragma unroll
    for (int i = 0; i < 7; ++i) {
      const s16x8 bf = *(const s16x8*)&cp[base + doff[i]];
      acc = __builtin_amdgcn_mfma_f32_16x16x32_bf16(wf[i], bf, acc, 0, 0, 0);
    }
    // C: row = quad*4+reg = channel, col = n = voxel
    const int Z = z0 + sz + wv, Y = y0 + sy + vy, X = x0 + sx + vx;
    const int gi = ((b * 64 + Z) * 64 + Y) * 64 + X;
    const float mv = (float)mask[gi];
    const float f0 = fmaxf(acc[0], 0.f) * mv;
    const float f1 = fmaxf(acc[1], 0.f) * mv;
    const float f2 = fmaxf(acc[2], 0.f) * mv;
    const float f3 = fmaxf(acc[3], 0.f) * mv;
    uint2* op = (uint2*)(yout + (size_t)gi * CH + quad * 4);
    op[0] = make_uint2(packbf(f0, f1), packbf(f2, f3));
  }
}

// ---- Stages 0..2: MFMA implicit GEMM, 4 voxel-groups per wave -------------
// Block = 256 voxels (wave = 64 vox = 4 m-groups of 16). Per tap i: 4
// independent A-loads + shared B ds_read + 4 independent MFMAs -> 4x
// load-level parallelism vs 1-chain R10. B prebuilt in global (bpre).
__global__ __launch_bounds__(256) void stage_mfma4(
    const u16* __restrict__ yin, const u16* __restrict__ bpre,
    const int* __restrict__ m_in_i, const float* __restrict__ m_in_f,
    u16* __restrict__ yout, float* __restrict__ m_out,
    float* __restrict__ pool_sum, float* __restrict__ cnt,
    const int S, const int stage)
{
  __shared__ u16 lb[14 * 512];          // 14 KB
  __shared__ float lC[4 * 16 * 17];
  __shared__ float lmp[256];

  const int So = S >> 1;
  const int nvox = So * So * So;
  const int b = blockIdx.y;
  const int tid = threadIdx.x;
  const int vg0 = blockIdx.x * 256;

  // copy prebuilt B fragments -> LDS (coalesced 16B)
  {
    const uint4* src = (const uint4*)bpre;
    uint4* dst = (uint4*)lb;
    for (int e = tid; e < 896; e += 256) dst[e] = src[e];
  }

  // pooled mask: each thread pools its own voxel
  {
    const int vox = vg0 + tid;
    const int oz = vox / (So * So);
    const int oy = (vox / So) % So;
    const int ox = vox % So;
    float mp = 0.f;
#pragma unroll
    for (int dz = 0; dz < 2; ++dz)
#pragma unroll
      for (int dy = 0; dy < 2; ++dy)
#pragma unroll
        for (int dx = 0; dx < 2; ++dx) {
          const int mi =
              ((b * S + 2 * oz + dz) * S + 2 * oy + dy) * S + 2 * ox + dx;
          const float mv = m_in_i ? (float)m_in_i[mi] : m_in_f[mi];
          mp = fmaxf(mp, mv);
        }
    lmp[tid] = mp;
  }
  __syncthreads();

  const int wv = tid >> 6;
  const int lane = tid & 63;
  const int m = lane & 15;
  const int quad = lane >> 4;
  const int qh = quad >> 1;
  const int qlo = quad & 1;

  int izb[4], iyb[4], ixb[4];
#pragma unroll
  for (int g = 0; g < 4; ++g) {
    const int vox = vg0 + wv * 64 + g * 16 + m;
    const int oz = vox / (So * So);
    const int oy = (vox / So) % So;
    const int ox = vox % So;
    izb[g] = 2 * oz - 1;
    iyb[g] = 2 * oy - 1;
    ixb[g] = 2 * ox - 1;
  }

  const s16x8* lbv = (const s16x8*)lb;
  f32x4 acc[4];
#pragma unroll
  for (int g = 0; g < 4; ++g) acc[g] = (f32x4){0.f, 0.f, 0.f, 0.f};

#pragma unroll
  for (int i = 0; i < 14; ++i) {
    const int t0 = 2 * i, t1 = 2 * i + 1;
    const int dz0 = t0 / 9, dy0 = (t0 / 3) % 3, dx0 = t0 % 3;
    const int dz1 = (t1 < 27) ? t1 / 9 : 1;
    const int dy1 = (t1 < 27) ? (t1 / 3) % 3 : 1;
    const int dx1 = (t1 < 27) ? t1 % 3 : 1;
    const int dzq = qh ? dz1 : dz0;
    const int dyq = qh ? dy1 : dy0;
    const int dxq = qh ? dx1 : dx0;

    uint4 ar[4];
#pragma unroll
    for (int g = 0; g < 4; ++g) {
      const int iz = izb[g] + dzq;
      const int iy = iyb[g] + dyq;
      const int ix = ixb[g] + dxq;
      const bool valid = (unsigned)iz < (unsigned)S &&
                         (unsigned)iy < (unsigned)S &&
                         (unsigned)ix < (unsigned)S;
      const int izc = min(max(iz, 0), S - 1);
      const int iyc = min(max(iy, 0), S - 1);
      const int ixc = min(max(ix, 0), S - 1);
      const size_t addr =
          (size_t)(((b * S + izc) * S + iyc) * S + ixc) * 16 + qlo * 8;
      uint4 v = *(const uint4*)(yin + addr);
      v.x = valid ? v.x : 0u;
      v.y = valid ? v.y : 0u;
      v.z = valid ? v.z : 0u;
      v.w = valid ? v.w : 0u;
      ar[g] = v;
    }
    const s16x8 bfrag = lbv[i * 64 + lane];
#pragma unroll
    for (int g = 0; g < 4; ++g)
      acc[g] = __builtin_amdgcn_mfma_f32_16x16x32_bf16(
          __builtin_bit_cast(s16x8, ar[g]), bfrag, acc[g], 0, 0, 0);
  }

  // epilogue: 4 phases through the small lC buffer
  float psum = 0.f;
#pragma unroll
  for (int g = 0; g < 4; ++g) {
    __syncthreads();                    // lC free
    {
      float* lCw = lC + wv * 272;
      const int n = lane & 15;
#pragma unroll
      for (int reg = 0; reg < 4; ++reg) {
        const int row = quad * 4 + reg;
        lCw[row * 17 + n] =
            fmaxf(acc[g][reg], 0.f) * lmp[wv * 64 + g * 16 + row];
      }
    }
    __syncthreads();                    // lC ready
    {
      const int vox_l = tid >> 2;
      const int cg = (tid & 3) * 4;
      const float* src = lC + (vox_l >> 4) * 272 + (vox_l & 15) * 17 + cg;
      const float f0 = src[0], f1 = src[1], f2 = src[2], f3 = src[3];
      const int lv = (vox_l >> 4) * 64 + g * 16 + (vox_l & 15);
      const size_t gi = (size_t)b * nvox + vg0 + lv;
      uint2* op = (uint2*)(yout + gi * 16 + cg);
      op[0] = make_uint2(packbf(f0, f1), packbf(f2, f3));
      if ((tid & 3) == 0) m_out[gi] = lmp[lv];
    }
    if (tid < 16) {
      float s = 0.f;
#pragma unroll 16
      for (int v = 0; v < 64; ++v)
        s += lC[(v >> 4) * 272 + (v & 15) * 17 + tid];
      psum += s;
    }
  }
  if (tid < 16) {
    atomicAdd(&pool_sum[(b * 6 + stage) * 16 + tid], psum);
  } else if (tid == 16) {
    float c = 0.f;
#pragma unroll 16
    for (int v = 0; v < 256; ++v) c += lmp[v];
    atomicAdd(&cnt[b * 6 + stage], c);
  }
}

// --------- Tail: stages 3,4,5 entirely in LDS + pools + full head MLP ------
__global__ __launch_bounds__(256) void tail_kernel(
    const u16* __restrict__ y3g, const float* __restrict__ m3g,
    const float* __restrict__ wstg,
    const float* __restrict__ meta, const float* __restrict__ sched,
    const float* __restrict__ mw1, const float* __restrict__ mb1,
    const float* __restrict__ mw2, const float* __restrict__ mb2,
    const float* __restrict__ matw, const float* __restrict__ matb,
    const float* __restrict__ schw, const float* __restrict__ schb,
    const float* __restrict__ f1w, const float* __restrict__ f1b,
    const float* __restrict__ f2w, const float* __restrict__ f2b,
    const float* __restrict__ pool_sum, const float* __restrict__ cnt,
    float* __restrict__ out)
{
  const int b = blockIdx.x;
  const int t = threadIdx.x;
  __shared__ float ly3[8 * 8 * 8 * 16];
  __shared__ float lm3[512];
  __shared__ float ly4[4 * 4 * 4 * 16];
  __shared__ float lm4[64];
  __shared__ float ly5[8 * 16];
  __shared__ float lm5[8];
  __shared__ float lsum[3][16];
  __shared__ float lcnt[3];
  __shared__ float invec[112];
  __shared__ float hbuf[32];
  __shared__ float zbuf[256];
  __shared__ float part[2];

  const uint4* yb = (const uint4*)(y3g + (size_t)b * 8192);
  for (int i = t; i < 1024; i += 256) {
    const uint4 p = yb[i];
    float* d = &ly3[i * 8];
    d[0] = bflo(p.x); d[1] = bfhi(p.x);
    d[2] = bflo(p.y); d[3] = bfhi(p.y);
    d[4] = bflo(p.z); d[5] = bfhi(p.z);
    d[6] = bflo(p.w); d[7] = bfhi(p.w);
  }
  for (int i = t; i < 512; i += 256) lm3[i] = m3g[b * 512 + i];
  __syncthreads();

  // ---- stage 3: 8^3 -> 4^3, thread = (vox, co-group of 4)
  {
    const float* w = wstg + 3 * 27 * 256;
    const int vox = t >> 2, cog = (t & 3) * 4;
    const int oz = vox >> 4, oy = (vox >> 2) & 3, ox = vox & 3;
    float acc[4] = {0.f, 0.f, 0.f, 0.f};
#pragma unroll
    for (int dz = 0; dz < 3; ++dz)
#pragma unroll
      for (int dy = 0; dy < 3; ++dy)
#pragma unroll
        for (int dx = 0; dx < 3; ++dx) {
          const int iz = 2 * oz + dz - 1, iy = 2 * oy + dy - 1,
                    ix = 2 * ox + dx - 1;
          const float s = ((unsigned)iz < 8u && (unsigned)iy < 8u &&
                           (unsigned)ix < 8u) ? 1.f : 0.f;
          const int idx = ((min(max(iz, 0), 7) * 8 + min(max(iy, 0), 7)) * 8 +
                           min(max(ix, 0), 7)) * 16;
          const float* wp = w + ((dz * 3 + dy) * 3 + dx) * 256;
#pragma unroll
          for (int ci = 0; ci < 16; ++ci) {
            const float v = ly3[idx + ci] * s;
#pragma unroll
            for (int c = 0; c < 4; ++c)
              acc[c] = fmaf(v, wp[ci * 16 + cog + c], acc[c]);
          }
        }
    float mp = 0.f;
#pragma unroll
    for (int dz = 0; dz < 2; ++dz)
#pragma unroll
      for (int dy = 0; dy < 2; ++dy)
#pragma unroll
        for (int dx = 0; dx < 2; ++dx)
          mp = fmaxf(mp, lm3[((2 * oz + dz) * 8 + 2 * oy + dy) * 8 +
                             2 * ox + dx]);
#pragma unroll
    for (int c = 0; c < 4; ++c)
      ly4[vox * 16 + cog + c] = fmaxf(acc[c], 0.f) * mp;
    if (cog == 0) lm4[vox] = mp;
  }
  __syncthreads();

  // ---- stage-3 sums and stage 4: 4^3 -> 2^3
  if (t < 16) {
    float s = 0.f;
#pragma unroll 16
    for (int v = 0; v < 64; ++v) s += ly4[v * 16 + t];
    lsum[0][t] = s;
  } else if (t == 16) {
    float s = 0.f;
#pragma unroll 16
    for (int v = 0; v < 64; ++v) s += lm4[v];
    lcnt[0] = s;
  }
  float s4val = 0.f, s4mp = 0.f;
  const int vox4 = (t >> 4) & 7, co4 = t & 15;
  if (t < 128) {
    const float* w = wstg + 4 * 27 * 256;
    const int oz = vox4 >> 2, oy = (vox4 >> 1) & 1, ox = vox4 & 1;
    float acc = 0.f;
#pragma unroll
    for (int dz = 0; dz < 3; ++dz)
#pragma unroll
      for (int dy = 0; dy < 3; ++dy)
#pragma unroll
        for (int dx = 0; dx < 3; ++dx) {
          const int iz = 2 * oz + dz - 1, iy = 2 * oy + dy - 1,
                    ix = 2 * ox + dx - 1;
          const float s = ((unsigned)iz < 4u && (unsigned)iy < 4u &&
                           (unsigned)ix < 4u) ? 1.f : 0.f;
          const int idx = ((min(max(iz, 0), 3) * 4 + min(max(iy, 0), 3)) * 4 +
                           min(max(ix, 0), 3)) * 16;
          const float* wp = w + ((dz * 3 + dy) * 3 + dx) * 256 + co4;
#pragma unroll
          for (int ci = 0; ci < 16; ++ci)
            acc = fmaf(ly4[idx + ci] * s, wp[ci * 16], acc);
        }
    float mp = 0.f;
#pragma unroll
    for (int dz = 0; dz < 2; ++dz)
#pragma unroll
      for (int dy = 0; dy < 2; ++dy)
#pragma unroll
        for (int dx = 0; dx < 2; ++dx)
          mp = fmaxf(mp, lm4[((2 * (vox4 >> 2) + dz) * 4 +
                              2 * ((vox4 >> 1) & 1) + dy) * 4 +
                             2 * (vox4 & 1) + dx]);
    s4val = fmaxf(acc, 0.f) * mp;
    s4mp = mp;
  }
  __syncthreads();
  if (t < 128) {
    ly5[vox4 * 16 + co4] = s4val;
    if (co4 == 0) lm5[vox4] = s4mp;
  }
  __syncthreads();

  // ---- stage-4 sums and stage 5: 2^3 -> 1
  if (t < 16) {
    float s = 0.f;
#pragma unroll
    for (int v = 0; v < 8; ++v) s += ly5[v * 16 + t];
    lsum[1][t] = s;
  } else if (t == 16) {
    lcnt[1] = lm5[0] + lm5[1] + lm5[2] + lm5[3] + lm5[4] + lm5[5] + lm5[6] +
              lm5[7];
  }
  if (t >= 64 && t < 80) {
    const int co = t - 64;
    const float* w = wstg + 5 * 27 * 256;
    float acc = 0.f;
#pragma unroll
    for (int dz = 0; dz < 3; ++dz)
#pragma unroll
      for (int dy = 0; dy < 3; ++dy)
#pragma unroll
        for (int dx = 0; dx < 3; ++dx) {
          const int iz = dz - 1, iy = dy - 1, ix = dx - 1;
          const float s = ((unsigned)iz < 2u && (unsigned)iy < 2u &&
                           (unsigned)ix < 2u) ? 1.f : 0.f;
          const int idx = ((min(max(iz, 0), 1) * 2 + min(max(iy, 0), 1)) * 2 +
                           min(max(ix, 0), 1)) * 16;
          const float* wp = w + ((dz * 3 + dy) * 3 + dx) * 256 + co;
#pragma unroll
          for (int ci = 0; ci < 16; ++ci)
            acc = fmaf(ly5[idx + ci] * s, wp[ci * 16], acc);
        }
    float mp = 0.f;
#pragma unroll
    for (int v = 0; v < 8; ++v) mp = fmaxf(mp, lm5[v]);
    lsum[2][co] = fmaxf(acc, 0.f) * mp;
    if (co == 0) lcnt[2] = mp;
  }
  __syncthreads();

  // ---- build invec; meta layer 1
  if (t < 48) {
    const int s = t >> 4;
    invec[t] = pool_sum[b * 96 + t] / fmaxf(cnt[b * 6 + s], 1.f);
  } else if (t < 96) {
    const int s = (t >> 4) - 3;
    invec[t] = lsum[s][t & 15] / fmaxf(lcnt[s], 1.f);
  } else if (t < 128) {
    const int j = t - 96;
    float h = mb1[j];
#pragma unroll
    for (int k = 0; k < 3; ++k) h = fmaf(meta[b * 3 + k], mw1[k * 32 + j], h);
    hbuf[j] = fmaxf(h, 0.f);
  }
  __syncthreads();
  if (t < 16) {
    float e = mb2[t];
#pragma unroll
    for (int j = 0; j < 32; ++j) e = fmaf(hbuf[j], mw2[j * 16 + t], e);
    invec[96 + t] = e;  // no ReLU on meta_emb
  }
  __syncthreads();
  if (t < 128) {
    float a = matb[t];
#pragma unroll 16
    for (int k = 0; k < 112; ++k) a = fmaf(invec[k], matw[k * 128 + t], a);
    zbuf[t] = fmaxf(a, 0.f);
    float s = schb[t];
#pragma unroll 16
    for (int k = 0; k < 128; ++k)
      s = fmaf(sched[b * 128 + k], schw[k * 128 + t], s);
    zbuf[128 + t] = fmaxf(s, 0.f);
  }
  __syncthreads();
  if (t < 128) {
    float a = f1b[t];
#pragma unroll 16
    for (int k = 0; k < 256; ++k) a = fmaf(zbuf[k], f1w[k * 128 + t], a);
    float v = fmaxf(a, 0.f) * f2w[t];
#pragma unroll
    for (int off = 32; off > 0; off >>= 1) v += __shfl_xor(v, off, 64);
    if ((t & 63) == 0) part[t >> 6] = v;
  }
  __syncthreads();
  if (t == 0) out[b] = part[0] + part[1] + f2b[0];
}

extern "C" void kernel_launch(void* const* d_in, const int* in_sizes, int n_in,
                              void* d_out, int out_size, void* d_ws,
                              size_t ws_size, hipStream_t stream)
{
  (void)in_sizes; (void)n_in; (void)out_size; (void)ws_size;
  const float* x      = (const float*)d_in[0];
  const int*   mask   = (const int*)  d_in[1];
  const float* meta   = (const float*)d_in[2];
  const float* sched  = (const float*)d_in[3];
  const float* w_stem = (const float*)d_in[4];
  const float* w_stg  = (const float*)d_in[5];
  const float* mw1    = (const float*)d_in[6];
  const float* mb1    = (const float*)d_in[7];
  const float* mw2    = (const float*)d_in[8];
  const float* mb2    = (const float*)d_in[9];
  const float* matw   = (const float*)d_in[10];
  const float* matb   = (const float*)d_in[11];
  const float* schw   = (const float*)d_in[12];
  const float* schb   = (const float*)d_in[13];
  const float* f1w    = (const float*)d_in[14];
  const float* f1b    = (const float*)d_in[15];
  const float* f2w    = (const float*)d_in[16];
  const float* f2b    = (const float*)d_in[17];
  float* out = (float*)d_out;

  char* ws = (char*)d_ws;
  size_t off = 0;
  auto alloc = [&](size_t nbytes) -> void* {
    void* p = ws + off;
    off += (nbytes + 255) & ~(size_t)255;
    return p;
  };

  u16* y0 = (u16*)alloc((size_t)NB * 64 * 64 * 64 * CH * 2);
  u16* y1 = (u16*)alloc((size_t)NB * 32 * 32 * 32 * CH * 2);
  u16* y2 = (u16*)alloc((size_t)NB * 16 * 16 * 16 * CH * 2);
  u16* y3 = (u16*)alloc((size_t)NB * 8 * 8 * 8 * CH * 2);
  float* m1 = (float*)alloc((size_t)NB * 32 * 32 * 32 * 4);
  float* m2 = (float*)alloc((size_t)NB * 16 * 16 * 16 * 4);
  float* m3 = (float*)alloc((size_t)NB * 8 * 8 * 8 * 4);
  float* pool_sum = (float*)alloc((NB * 96 + NB * 6) * 4);
  float* cnt = pool_sum + NB * 96;
  u16* bpre = (u16*)alloc(3 * 7168 * 2);

  bprep_kernel<<<84, 256, 0, stream>>>(w_stg, bpre);

  stem_mfma<<<dim3(512, NB), 256, 0, stream>>>(x, mask, w_stem, y0,
                                               pool_sum, cnt);

  // stage 0: 64->32 (32768 vox / 256 = 128 blocks/batch)
  stage_mfma4<<<dim3(128, NB), 256, 0, stream>>>(
      y0, bpre + 0 * 7168, mask, (const float*)nullptr, y1, m1,
      pool_sum, cnt, 64, 0);
  // stage 1: 32->16 (16 blocks/batch)
  stage_mfma4<<<dim3(16, NB), 256, 0, stream>>>(
      y1, bpre + 1 * 7168, (const int*)nullptr, m1, y2, m2,
      pool_sum, cnt, 32, 1);
  // stage 2: 16->8 (2 blocks/batch)
  stage_mfma4<<<dim3(2, NB), 256, 0, stream>>>(
      y2, bpre + 2 * 7168, (const int*)nullptr, m2, y3, m3,
      pool_sum, cnt, 16, 2);

  tail_kernel<<<NB, 256, 0, stream>>>(y3, m3, w_stg, meta, sched,
                                      mw1, mb1, mw2, mb2, matw, matb,
                                      schw, schb, f1w, f1b, f2w, f2b,
                                      pool_sum, cnt, out);
}

// Round 2
// 212.813 us; speedup vs baseline: 1.1511x; 1.0682x over previous
//
#include <hip/hip_runtime.h>

#define CH 16
#define NB 8

typedef unsigned short u16;
typedef unsigned int u32;
typedef __attribute__((ext_vector_type(8))) short s16x8;
typedef __attribute__((ext_vector_type(4))) float f32x4;

__device__ __forceinline__ float bflo(u32 u) { return __uint_as_float(u << 16); }
__device__ __forceinline__ float bfhi(u32 u) { return __uint_as_float(u & 0xffff0000u); }
__device__ __forceinline__ u32 bfrnd(float f) {
  u32 u = __float_as_uint(f);
  return (u + 0x7fffu + ((u >> 16) & 1u)) >> 16;
}
__device__ __forceinline__ u32 packbf(float lo, float hi) {
  return bfrnd(lo) | (bfrnd(hi) << 16);
}

// ---- Prep: build bf16 B-fragments for MFMA stages 0..3 (once) -------------
__global__ __launch_bounds__(256) void bprep_kernel(
    const float* __restrict__ w_stg, u16* __restrict__ bpre)
{
  const int e = blockIdx.x * 256 + (int)threadIdx.x;
  if (e >= 4 * 7168) return;
  const int s = e / 7168, r0 = e % 7168;
  const int i = r0 >> 9;
  const int r = r0 & 511;
  const int l = r >> 3, j = r & 7;
  const int tap = 2 * i + (l >> 5);
  const int cin = ((l >> 4) & 1) * 8 + j;
  const int n = l & 15;
  const float* w = w_stg + s * 27 * 256;
  const float val = (tap < 27) ? w[(tap * 16 + cin) * 16 + n] : 0.f;
  bpre[s * 7168 + i * 512 + l * 8 + j] = (u16)bfrnd(val);
}

// ---- Stem via MFMA implicit GEMM, vector-gather form (unchanged R1) -------
__global__ __launch_bounds__(256) void stem_mfma(
    const float* __restrict__ x, const int* __restrict__ mask,
    const float* __restrict__ wst, u16* __restrict__ yout,
    float* __restrict__ pool_sum, float* __restrict__ cnt)
{
  __shared__ u16 tl[144 * 24];      // linear halo tile, row stride 24 u16
  __shared__ u16 cp[8 * 1168];      // 8 shifted copies, stride 1168 u16

  const int b = blockIdx.y;
  const int u = blockIdx.x;
  const int tb = ((u & 7) << 6) | (u >> 3);
  const int z0 = (tb >> 6) * 8;
  const int y0 = ((tb >> 3) & 7) * 8;
  const int x0 = (tb & 7) * 8;
  const int tid = threadIdx.x;

  if (tb == 0) {
    if (tid < 96) pool_sum[b * 96 + tid] = 0.f;
    else if (tid < 102) cnt[b * 6 + (tid - 96)] = 0.f;
  }

  const int lane = tid & 63;
  const int wv = tid >> 6;
  const int n = lane & 15;
  const int quad = lane >> 4;
  const int vy = n >> 2, vx = n & 3;

  s16x8 wf[7];
#pragma unroll
  for (int i = 0; i < 7; ++i) {
    const int r = i * 4 + quad;
#pragma unroll
    for (int j = 0; j < 8; ++j) {
      float v = 0.f;
      if (r < 25 && j < 5) v = wst[(r * 5 + j) * 16 + n];
      wf[i][j] = (short)bfrnd(v);
    }
  }

  for (int i = tid; i < 1728; i += 256) {
    const int row = i / 12;
    const int lx = i - row * 12;
    const int lz = row / 12;
    const int ly = row - lz * 12;
    const int gz = z0 + lz - 2, gy = y0 + ly - 2, gx = x0 + lx - 2;
    float v = 0.f;
    if ((unsigned)gz < 64u && (unsigned)gy < 64u && (unsigned)gx < 64u) {
      const int gi = ((b * 64 + gz) * 64 + gy) * 64 + gx;
      v = x[gi] * (float)mask[gi];
    }
    tl[row * 24 + lx] = (u16)bfrnd(v);
  }
  __syncthreads();

  if (tid < 144) {
    const uint4 a = *(const uint4*)&tl[tid * 24];
    const uint2 bq = *(const uint2*)&tl[tid * 24 + 8];
    u32 c[7];
    c[0] = a.x; c[1] = a.y; c[2] = a.z; c[3] = a.w;
    c[4] = bq.x; c[5] = bq.y; c[6] = 0u;
    u32 d[7];
#pragma unroll
    for (int k = 0; k < 6; ++k) d[k] = (c[k] >> 16) | (c[k + 1] << 16);
    d[6] = c[6] >> 16;
    uint4* dst = (uint4*)&cp[tid * 8];
    dst[0 * 146] = make_uint4(c[0], c[1], c[2], c[3]);
    dst[1 * 146] = make_uint4(d[0], d[1], d[2], d[3]);
    dst[2 * 146] = make_uint4(c[1], c[2], c[3], c[4]);
    dst[3 * 146] = make_uint4(d[1], d[2], d[3], d[4]);
    dst[4 * 146] = make_uint4(c[2], c[3], c[4], c[5]);
    dst[5 * 146] = make_uint4(d[2], d[3], d[4], d[5]);
    dst[6 * 146] = make_uint4(c[3], c[4], c[5], c[6]);
    dst[7 * 146] = make_uint4(d[3], d[4], d[5], d[6]);
  }
  __syncthreads();

  int doff[7];
#pragma unroll
  for (int i = 0; i < 7; ++i) {
    const int r = i * 4 + quad;
    doff[i] = (r < 25) ? ((r / 5) * 12 + (r % 5)) * 8 : 0;
  }

  for (int s = 0; s < 8; ++s) {
    const int sz = (s >> 2) * 4, sy = ((s >> 1) & 1) * 4, sx = (s & 1) * 4;
    const int base =
        (sx + vx) * 1168 + (((sz + wv) * 12) + (sy + vy)) * 8;
    f32x4 acc = {0.f, 0.f, 0.f, 0.f};
#pragma unroll
    for (int i = 0; i < 7; ++i) {
      const s16x8 bf = *(const s16x8*)&cp[base + doff[i]];
      acc = __builtin_amdgcn_mfma_f32_16x16x32_bf16(wf[i], bf, acc, 0, 0, 0);
    }
    const int Z = z0 + sz + wv, Y = y0 + sy + vy, X = x0 + sx + vx;
    const int gi = ((b * 64 + Z) * 64 + Y) * 64 + X;
    const float mv = (float)mask[gi];
    const float f0 = fmaxf(acc[0], 0.f) * mv;
    const float f1 = fmaxf(acc[1], 0.f) * mv;
    const float f2 = fmaxf(acc[2], 0.f) * mv;
    const float f3 = fmaxf(acc[3], 0.f) * mv;
    uint2* op = (uint2*)(yout + (size_t)gi * CH + quad * 4);
    op[0] = make_uint2(packbf(f0, f1), packbf(f2, f3));
  }
}

// ---- Stages 0..2: MFMA implicit GEMM, 4 voxel-groups per wave (unchanged) -
__global__ __launch_bounds__(256) void stage_mfma4(
    const u16* __restrict__ yin, const u16* __restrict__ bpre,
    const int* __restrict__ m_in_i, const float* __restrict__ m_in_f,
    u16* __restrict__ yout, float* __restrict__ m_out,
    float* __restrict__ pool_sum, float* __restrict__ cnt,
    const int S, const int stage)
{
  __shared__ u16 lb[14 * 512];
  __shared__ float lC[4 * 16 * 17];
  __shared__ float lmp[256];

  const int So = S >> 1;
  const int nvox = So * So * So;
  const int b = blockIdx.y;
  const int tid = threadIdx.x;
  const int vg0 = blockIdx.x * 256;

  {
    const uint4* src = (const uint4*)bpre;
    uint4* dst = (uint4*)lb;
    for (int e = tid; e < 896; e += 256) dst[e] = src[e];
  }

  {
    const int vox = vg0 + tid;
    const int oz = vox / (So * So);
    const int oy = (vox / So) % So;
    const int ox = vox % So;
    float mp = 0.f;
#pragma unroll
    for (int dz = 0; dz < 2; ++dz)
#pragma unroll
      for (int dy = 0; dy < 2; ++dy)
#pragma unroll
        for (int dx = 0; dx < 2; ++dx) {
          const int mi =
              ((b * S + 2 * oz + dz) * S + 2 * oy + dy) * S + 2 * ox + dx;
          const float mv = m_in_i ? (float)m_in_i[mi] : m_in_f[mi];
          mp = fmaxf(mp, mv);
        }
    lmp[tid] = mp;
  }
  __syncthreads();

  const int wv = tid >> 6;
  const int lane = tid & 63;
  const int m = lane & 15;
  const int quad = lane >> 4;
  const int qh = quad >> 1;
  const int qlo = quad & 1;

  int izb[4], iyb[4], ixb[4];
#pragma unroll
  for (int g = 0; g < 4; ++g) {
    const int vox = vg0 + wv * 64 + g * 16 + m;
    const int oz = vox / (So * So);
    const int oy = (vox / So) % So;
    const int ox = vox % So;
    izb[g] = 2 * oz - 1;
    iyb[g] = 2 * oy - 1;
    ixb[g] = 2 * ox - 1;
  }

  const s16x8* lbv = (const s16x8*)lb;
  f32x4 acc[4];
#pragma unroll
  for (int g = 0; g < 4; ++g) acc[g] = (f32x4){0.f, 0.f, 0.f, 0.f};

#pragma unroll
  for (int i = 0; i < 14; ++i) {
    const int t0 = 2 * i, t1 = 2 * i + 1;
    const int dz0 = t0 / 9, dy0 = (t0 / 3) % 3, dx0 = t0 % 3;
    const int dz1 = (t1 < 27) ? t1 / 9 : 1;
    const int dy1 = (t1 < 27) ? (t1 / 3) % 3 : 1;
    const int dx1 = (t1 < 27) ? t1 % 3 : 1;
    const int dzq = qh ? dz1 : dz0;
    const int dyq = qh ? dy1 : dy0;
    const int dxq = qh ? dx1 : dx0;

    uint4 ar[4];
#pragma unroll
    for (int g = 0; g < 4; ++g) {
      const int iz = izb[g] + dzq;
      const int iy = iyb[g] + dyq;
      const int ix = ixb[g] + dxq;
      const bool valid = (unsigned)iz < (unsigned)S &&
                         (unsigned)iy < (unsigned)S &&
                         (unsigned)ix < (unsigned)S;
      const int izc = min(max(iz, 0), S - 1);
      const int iyc = min(max(iy, 0), S - 1);
      const int ixc = min(max(ix, 0), S - 1);
      const size_t addr =
          (size_t)(((b * S + izc) * S + iyc) * S + ixc) * 16 + qlo * 8;
      uint4 v = *(const uint4*)(yin + addr);
      v.x = valid ? v.x : 0u;
      v.y = valid ? v.y : 0u;
      v.z = valid ? v.z : 0u;
      v.w = valid ? v.w : 0u;
      ar[g] = v;
    }
    const s16x8 bfrag = lbv[i * 64 + lane];
#pragma unroll
    for (int g = 0; g < 4; ++g)
      acc[g] = __builtin_amdgcn_mfma_f32_16x16x32_bf16(
          __builtin_bit_cast(s16x8, ar[g]), bfrag, acc[g], 0, 0, 0);
  }

  float psum = 0.f;
#pragma unroll
  for (int g = 0; g < 4; ++g) {
    __syncthreads();
    {
      float* lCw = lC + wv * 272;
      const int n = lane & 15;
#pragma unroll
      for (int reg = 0; reg < 4; ++reg) {
        const int row = quad * 4 + reg;
        lCw[row * 17 + n] =
            fmaxf(acc[g][reg], 0.f) * lmp[wv * 64 + g * 16 + row];
      }
    }
    __syncthreads();
    {
      const int vox_l = tid >> 2;
      const int cg = (tid & 3) * 4;
      const float* src = lC + (vox_l >> 4) * 272 + (vox_l & 15) * 17 + cg;
      const float f0 = src[0], f1 = src[1], f2 = src[2], f3 = src[3];
      const int lv = (vox_l >> 4) * 64 + g * 16 + (vox_l & 15);
      const size_t gi = (size_t)b * nvox + vg0 + lv;
      uint2* op = (uint2*)(yout + gi * 16 + cg);
      op[0] = make_uint2(packbf(f0, f1), packbf(f2, f3));
      if ((tid & 3) == 0) m_out[gi] = lmp[lv];
    }
    if (tid < 16) {
      float s = 0.f;
#pragma unroll 16
      for (int v = 0; v < 64; ++v)
        s += lC[(v >> 4) * 272 + (v & 15) * 17 + tid];
      psum += s;
    }
  }
  if (tid < 16) {
    atomicAdd(&pool_sum[(b * 6 + stage) * 16 + tid], psum);
  } else if (tid == 16) {
    float c = 0.f;
#pragma unroll 16
    for (int v = 0; v < 256; ++v) c += lmp[v];
    atomicAdd(&cnt[b * 6 + stage], c);
  }
}

// --------- Tail: stage 3 via MFMA (K split over 4 waves), stages 4/5 via
// split-K VALU, MLP head with parallel halves. One block per batch. ---------
__global__ __launch_bounds__(256) void tail_kernel(
    const u16* __restrict__ y3g, const float* __restrict__ m3g,
    const u16* __restrict__ bpre,
    const float* __restrict__ wstg,
    const float* __restrict__ meta, const float* __restrict__ sched,
    const float* __restrict__ mw1, const float* __restrict__ mb1,
    const float* __restrict__ mw2, const float* __restrict__ mb2,
    const float* __restrict__ matw, const float* __restrict__ matb,
    const float* __restrict__ schw, const float* __restrict__ schb,
    const float* __restrict__ f1w, const float* __restrict__ f1b,
    const float* __restrict__ f2w, const float* __restrict__ f2b,
    const float* __restrict__ pool_sum, const float* __restrict__ cnt,
    float* __restrict__ out)
{
  const int b = blockIdx.x;
  const int t = threadIdx.x;
  __shared__ u16 ty3[8192];           // y3 in bf16 (16 KB)
  __shared__ float lm3[512];
  __shared__ float pb[4 * 64 * 17];   // stage-3 wave partials (pad 17)
  __shared__ float ly4[64 * 16];
  __shared__ float lm4[64];
  __shared__ float ps4[256];
  __shared__ float ly5[8 * 16];
  __shared__ float lm5[8];
  __shared__ float ps5[128];
  __shared__ float lsum[3][16];
  __shared__ float lcnt[3];
  __shared__ float invec[112];
  __shared__ float hbuf[32];
  __shared__ float zbuf[256];
  __shared__ float psf[256];
  __shared__ float part[2];

  // ---- P0: load y3 (bf16) + m3
  {
    const uint4* yb = (const uint4*)(y3g + (size_t)b * 8192);
    uint4* dst = (uint4*)ty3;
    for (int i = t; i < 1024; i += 256) dst[i] = yb[i];
    for (int i = t; i < 512; i += 256) lm3[i] = m3g[b * 512 + i];
  }
  __syncthreads();

  // ---- P1: stage 3 MFMA, tap-pairs split across waves
  {
    const int lane = t & 63;
    const int wv = t >> 6;
    const int mm = lane & 15;
    const int quad = lane >> 4;
    const int qh = quad >> 1, qlo = quad & 1;

    int iz0[4], iy0[4], ix0[4];
#pragma unroll
    for (int g = 0; g < 4; ++g) {
      const int vox = g * 16 + mm;
      iz0[g] = 2 * (vox >> 4) - 1;
      iy0[g] = 2 * ((vox >> 2) & 3) - 1;
      ix0[g] = 2 * (vox & 3) - 1;
    }
    f32x4 a3[4];
#pragma unroll
    for (int g = 0; g < 4; ++g) a3[g] = (f32x4){0.f, 0.f, 0.f, 0.f};
    const s16x8* bp3 = (const s16x8*)(bpre + 3 * 7168);
#pragma unroll
    for (int ii = 0; ii < 4; ++ii) {
      const int i = wv * 4 + ii;
      if (i < 14) {
        const int t0 = 2 * i, t1 = 2 * i + 1;
        const int dz0 = t0 / 9, dy0 = (t0 / 3) % 3, dx0 = t0 % 3;
        const int dz1 = (t1 < 27) ? t1 / 9 : 1;
        const int dy1 = (t1 < 27) ? (t1 / 3) % 3 : 1;
        const int dx1 = (t1 < 27) ? t1 % 3 : 1;
        const int dzq = qh ? dz1 : dz0;
        const int dyq = qh ? dy1 : dy0;
        const int dxq = qh ? dx1 : dx0;
        uint4 ar[4];
#pragma unroll
        for (int g = 0; g < 4; ++g) {
          const int iz = iz0[g] + dzq;
          const int iy = iy0[g] + dyq;
          const int ix = ix0[g] + dxq;
          const bool valid = (unsigned)iz < 8u && (unsigned)iy < 8u &&
                             (unsigned)ix < 8u;
          const int izc = min(max(iz, 0), 7);
          const int iyc = min(max(iy, 0), 7);
          const int ixc = min(max(ix, 0), 7);
          const int ad = ((izc * 8 + iyc) * 8 + ixc) * 16 + qlo * 8;
          uint4 v = *(const uint4*)&ty3[ad];
          v.x = valid ? v.x : 0u;
          v.y = valid ? v.y : 0u;
          v.z = valid ? v.z : 0u;
          v.w = valid ? v.w : 0u;
          ar[g] = v;
        }
        const s16x8 bf = bp3[i * 64 + lane];
#pragma unroll
        for (int g = 0; g < 4; ++g)
          a3[g] = __builtin_amdgcn_mfma_f32_16x16x32_bf16(
              __builtin_bit_cast(s16x8, ar[g]), bf, a3[g], 0, 0, 0);
      }
    }
#pragma unroll
    for (int g = 0; g < 4; ++g)
#pragma unroll
      for (int reg = 0; reg < 4; ++reg)
        pb[wv * 1088 + (g * 16 + quad * 4 + reg) * 17 + mm] = a3[g][reg];
  }
  __syncthreads();

  // ---- P2: reduce 4 wave-partials -> relu * mask -> ly4 (f32)
  {
    const int vox = t >> 2, cg = (t & 3) * 4;
    const int oz = vox >> 4, oy = (vox >> 2) & 3, ox = vox & 3;
    float mp = 0.f;
#pragma unroll
    for (int dz = 0; dz < 2; ++dz)
#pragma unroll
      for (int dy = 0; dy < 2; ++dy)
#pragma unroll
        for (int dx = 0; dx < 2; ++dx)
          mp = fmaxf(mp, lm3[((2 * oz + dz) * 8 + 2 * oy + dy) * 8 +
                             2 * ox + dx]);
#pragma unroll
    for (int c = 0; c < 4; ++c) {
      const int ch = cg + c;
      const float s = pb[vox * 17 + ch] + pb[1088 + vox * 17 + ch] +
                      pb[2176 + vox * 17 + ch] + pb[3264 + vox * 17 + ch];
      ly4[vox * 16 + ch] = fmaxf(s, 0.f) * mp;
    }
    if (cg == 0) lm4[vox] = mp;
  }
  __syncthreads();

  // ---- P3: stage-3 pools + stage 4 split-K (all 256 threads)
  if (t < 16) {
    float s = 0.f;
#pragma unroll 16
    for (int v = 0; v < 64; ++v) s += ly4[v * 16 + t];
    lsum[0][t] = s;
  } else if (t == 16) {
    float s = 0.f;
#pragma unroll 16
    for (int v = 0; v < 64; ++v) s += lm4[v];
    lcnt[0] = s;
  }
  {
    const float* w = wstg + 4 * 27 * 256;
    const int o = t >> 1, kh = t & 1;
    const int vox4 = o >> 4, co = o & 15;
    const int oz = vox4 >> 2, oy = (vox4 >> 1) & 1, ox = vox4 & 1;
    float acc = 0.f;
#pragma unroll
    for (int tt = 0; tt < 14; ++tt) {
      const int tap = tt + (kh ? 14 : 0);
      if (tap < 27) {
        const int dz = tap / 9, dy = (tap / 3) % 3, dx = tap % 3;
        const int iz = 2 * oz + dz - 1, iy = 2 * oy + dy - 1,
                  ix = 2 * ox + dx - 1;
        const float s = ((unsigned)iz < 4u && (unsigned)iy < 4u &&
                         (unsigned)ix < 4u) ? 1.f : 0.f;
        const int idx = ((min(max(iz, 0), 3) * 4 + min(max(iy, 0), 3)) * 4 +
                         min(max(ix, 0), 3)) * 16;
        const float* wp = w + tap * 256 + co;
#pragma unroll
        for (int ci = 0; ci < 16; ++ci)
          acc = fmaf(ly4[idx + ci] * s, wp[ci * 16], acc);
      }
    }
    ps4[t] = acc;
  }
  __syncthreads();

  // ---- P4: combine stage-4 partials -> ly5
  if (t < 128) {
    const int vox4 = t >> 4, co = t & 15;
    float mp = 0.f;
#pragma unroll
    for (int dz = 0; dz < 2; ++dz)
#pragma unroll
      for (int dy = 0; dy < 2; ++dy)
#pragma unroll
        for (int dx = 0; dx < 2; ++dx)
          mp = fmaxf(mp, lm4[((2 * (vox4 >> 2) + dz) * 4 +
                              2 * ((vox4 >> 1) & 1) + dy) * 4 +
                             2 * (vox4 & 1) + dx]);
    ly5[t] = fmaxf(ps4[2 * t] + ps4[2 * t + 1], 0.f) * mp;
    if (co == 0) lm5[vox4] = mp;
  }
  __syncthreads();

  // ---- P5: stage-4 pools + stage 5 split-K (128 threads, 8 K-slices)
  if (t < 16) {
    float s = 0.f;
#pragma unroll
    for (int v = 0; v < 8; ++v) s += ly5[v * 16 + t];
    lsum[1][t] = s;
  } else if (t == 16) {
    lcnt[1] = lm5[0] + lm5[1] + lm5[2] + lm5[3] + lm5[4] + lm5[5] + lm5[6] +
              lm5[7];
  }
  if (t < 128) {
    const float* w = wstg + 5 * 27 * 256;
    const int co = t & 15, k8 = t >> 4;
    float acc = 0.f;
#pragma unroll
    for (int tt = 0; tt < 4; ++tt) {
      const int tap = k8 * 4 + tt;
      if (tap < 27) {
        const int dz = tap / 9, dy = (tap / 3) % 3, dx = tap % 3;
        const int iz = dz - 1, iy = dy - 1, ix = dx - 1;
        const float s = ((unsigned)iz < 2u && (unsigned)iy < 2u &&
                         (unsigned)ix < 2u) ? 1.f : 0.f;
        const int idx = ((min(max(iz, 0), 1) * 2 + min(max(iy, 0), 1)) * 2 +
                         min(max(ix, 0), 1)) * 16;
        const float* wp = w + tap * 256 + co;
#pragma unroll
        for (int ci = 0; ci < 16; ++ci)
          acc = fmaf(ly5[idx + ci] * s, wp[ci * 16], acc);
      }
    }
    ps5[t] = acc;
  }
  __syncthreads();

  // ---- P6: combine stage-5 partials; meta layer 1
  if (t < 16) {
    float s = ps5[t] + ps5[16 + t] + ps5[32 + t] + ps5[48 + t] +
              ps5[64 + t] + ps5[80 + t] + ps5[96 + t] + ps5[112 + t];
    float mp = 0.f;
#pragma unroll
    for (int v = 0; v < 8; ++v) mp = fmaxf(mp, lm5[v]);
    lsum[2][t] = fmaxf(s, 0.f) * mp;
    if (t == 0) lcnt[2] = mp;
  } else if (t >= 96 && t < 128) {
    const int j = t - 96;
    float h = mb1[j];
#pragma unroll
    for (int k = 0; k < 3; ++k) h = fmaf(meta[b * 3 + k], mw1[k * 32 + j], h);
    hbuf[j] = fmaxf(h, 0.f);
  }
  __syncthreads();

  // ---- P7: build invec (pools from global + local; meta_emb)
  if (t < 48) {
    const int s = t >> 4;
    invec[t] = pool_sum[b * 96 + t] / fmaxf(cnt[b * 6 + s], 1.f);
  } else if (t < 96) {
    const int s = (t >> 4) - 3;
    invec[t] = lsum[s][t & 15] / fmaxf(lcnt[s], 1.f);
  } else if (t < 112) {
    const int j = t - 96;
    float e = mb2[j];
#pragma unroll
    for (int k = 0; k < 32; ++k) e = fmaf(hbuf[k], mw2[k * 16 + j], e);
    invec[t] = e;  // no ReLU on meta_emb
  }
  __syncthreads();

  // ---- P8: zbuf = [relu(invec@matw), relu(sched@schw)] in parallel halves
  if (t < 128) {
    float a = matb[t];
#pragma unroll 16
    for (int k = 0; k < 112; ++k) a = fmaf(invec[k], matw[k * 128 + t], a);
    zbuf[t] = fmaxf(a, 0.f);
  } else {
    const int c = t - 128;
    float s = schb[c];
#pragma unroll 16
    for (int k = 0; k < 128; ++k)
      s = fmaf(sched[b * 128 + k], schw[k * 128 + c], s);
    zbuf[128 + c] = fmaxf(s, 0.f);
  }
  __syncthreads();

  // ---- P9: f1 with K split across thread halves
  {
    const int col = t & 127, kh = t >> 7;
    float a = 0.f;
#pragma unroll 16
    for (int kk = 0; kk < 128; ++kk) {
      const int k = kh * 128 + kk;
      a = fmaf(zbuf[k], f1w[k * 128 + col], a);
    }
    psf[t] = a;
  }
  __syncthreads();

  // ---- P10: final combine + dot with f2w
  if (t < 128) {
    const float a = psf[t] + psf[128 + t] + f1b[t];
    float v = fmaxf(a, 0.f) * f2w[t];
#pragma unroll
    for (int off = 32; off > 0; off >>= 1) v += __shfl_xor(v, off, 64);
    if ((t & 63) == 0) part[t >> 6] = v;
  }
  __syncthreads();
  if (t == 0) out[b] = part[0] + part[1] + f2b[0];
}

extern "C" void kernel_launch(void* const* d_in, const int* in_sizes, int n_in,
                              void* d_out, int out_size, void* d_ws,
                              size_t ws_size, hipStream_t stream)
{
  (void)in_sizes; (void)n_in; (void)out_size; (void)ws_size;
  const float* x      = (const float*)d_in[0];
  const int*   mask   = (const int*)  d_in[1];
  const float* meta   = (const float*)d_in[2];
  const float* sched  = (const float*)d_in[3];
  const float* w_stem = (const float*)d_in[4];
  const float* w_stg  = (const float*)d_in[5];
  const float* mw1    = (const float*)d_in[6];
  const float* mb1    = (const float*)d_in[7];
  const float* mw2    = (const float*)d_in[8];
  const float* mb2    = (const float*)d_in[9];
  const float* matw   = (const float*)d_in[10];
  const float* matb   = (const float*)d_in[11];
  const float* schw   = (const float*)d_in[12];
  const float* schb   = (const float*)d_in[13];
  const float* f1w    = (const float*)d_in[14];
  const float* f1b    = (const float*)d_in[15];
  const float* f2w    = (const float*)d_in[16];
  const float* f2b    = (const float*)d_in[17];
  float* out = (float*)d_out;

  char* ws = (char*)d_ws;
  size_t off = 0;
  auto alloc = [&](size_t nbytes) -> void* {
    void* p = ws + off;
    off += (nbytes + 255) & ~(size_t)255;
    return p;
  };

  u16* y0 = (u16*)alloc((size_t)NB * 64 * 64 * 64 * CH * 2);
  u16* y1 = (u16*)alloc((size_t)NB * 32 * 32 * 32 * CH * 2);
  u16* y2 = (u16*)alloc((size_t)NB * 16 * 16 * 16 * CH * 2);
  u16* y3 = (u16*)alloc((size_t)NB * 8 * 8 * 8 * CH * 2);
  float* m1 = (float*)alloc((size_t)NB * 32 * 32 * 32 * 4);
  float* m2 = (float*)alloc((size_t)NB * 16 * 16 * 16 * 4);
  float* m3 = (float*)alloc((size_t)NB * 8 * 8 * 8 * 4);
  float* pool_sum = (float*)alloc((NB * 96 + NB * 6) * 4);
  float* cnt = pool_sum + NB * 96;
  u16* bpre = (u16*)alloc(4 * 7168 * 2);

  bprep_kernel<<<112, 256, 0, stream>>>(w_stg, bpre);

  stem_mfma<<<dim3(512, NB), 256, 0, stream>>>(x, mask, w_stem, y0,
                                               pool_sum, cnt);

  // stage 0: 64->32 (32768 vox / 256 = 128 blocks/batch)
  stage_mfma4<<<dim3(128, NB), 256, 0, stream>>>(
      y0, bpre + 0 * 7168, mask, (const float*)nullptr, y1, m1,
      pool_sum, cnt, 64, 0);
  // stage 1: 32->16 (16 blocks/batch)
  stage_mfma4<<<dim3(16, NB), 256, 0, stream>>>(
      y1, bpre + 1 * 7168, (const int*)nullptr, m1, y2, m2,
      pool_sum, cnt, 32, 1);
  // stage 2: 16->8 (2 blocks/batch)
  stage_mfma4<<<dim3(2, NB), 256, 0, stream>>>(
      y2, bpre + 2 * 7168, (const int*)nullptr, m2, y3, m3,
      pool_sum, cnt, 16, 2);

  tail_kernel<<<NB, 256, 0, stream>>>(y3, m3, bpre, w_stg, meta, sched,
                                      mw1, mb1, mw2, mb2, matw, matb,
                                      schw, schb, f1w, f1b, f2w, f2b,
                                      pool_sum, cnt, out);
}

// Round 3
// 203.757 us; speedup vs baseline: 1.2023x; 1.0444x over previous
//
#include <hip/hip_runtime.h>

#define CH 16
#define NB 8

typedef unsigned short u16;
typedef unsigned int u32;
typedef __attribute__((ext_vector_type(8))) short s16x8;
typedef __attribute__((ext_vector_type(4))) float f32x4;

__device__ __forceinline__ float bflo(u32 u) { return __uint_as_float(u << 16); }
__device__ __forceinline__ float bfhi(u32 u) { return __uint_as_float(u & 0xffff0000u); }
__device__ __forceinline__ u32 bfrnd(float f) {
  u32 u = __float_as_uint(f);
  return (u + 0x7fffu + ((u >> 16) & 1u)) >> 16;
}
__device__ __forceinline__ u32 packbf(float lo, float hi) {
  return bfrnd(lo) | (bfrnd(hi) << 16);
}

// ---- Prep: bf16 B-fragments for MFMA stages 0..3 + stem A-fragments -------
// bpre layout: [0 .. 4*7168)  : stage 0..3 B-fragments (as before)
//              [4*7168 .. +3584): stem weight fragments [i=0..6][lane][j=0..7]
__global__ __launch_bounds__(256) void bprep_kernel(
    const float* __restrict__ w_stg, const float* __restrict__ w_stem,
    u16* __restrict__ bpre)
{
  const int e = blockIdx.x * 256 + (int)threadIdx.x;
  if (e >= 4 * 7168 + 3584) return;
  if (e < 4 * 7168) {
    const int s = e / 7168, r0 = e % 7168;
    const int i = r0 >> 9;
    const int r = r0 & 511;
    const int l = r >> 3, j = r & 7;
    const int tap = 2 * i + (l >> 5);
    const int cin = ((l >> 4) & 1) * 8 + j;
    const int n = l & 15;
    const float* w = w_stg + s * 27 * 256;
    const float val = (tap < 27) ? w[(tap * 16 + cin) * 16 + n] : 0.f;
    bpre[s * 7168 + i * 512 + l * 8 + j] = (u16)bfrnd(val);
  } else {
    const int e2 = e - 4 * 7168;          // [i][lane][j]
    const int i = e2 >> 9;
    const int r0 = e2 & 511;
    const int lane = r0 >> 3, j = r0 & 7;
    const int quad = lane >> 4, n = lane & 15;
    const int r = i * 4 + quad;
    const float val = (r < 25 && j < 5) ? w_stem[(r * 5 + j) * 16 + n] : 0.f;
    bpre[4 * 7168 + e2] = (u16)bfrnd(val);
  }
}

// ---- Stem via MFMA implicit GEMM, prebuilt weight fragments ---------------
__global__ __launch_bounds__(256) void stem_mfma(
    const float* __restrict__ x, const int* __restrict__ mask,
    const u16* __restrict__ bpre, u16* __restrict__ yout,
    float* __restrict__ pool_sum, float* __restrict__ cnt)
{
  __shared__ u16 tl[144 * 24];      // linear halo tile, row stride 24 u16
  __shared__ u16 cp[8 * 1168];      // 8 shifted copies, stride 1168 u16

  const int b = blockIdx.y;
  const int u = blockIdx.x;
  const int tb = ((u & 7) << 6) | (u >> 3);
  const int z0 = (tb >> 6) * 8;
  const int y0 = ((tb >> 3) & 7) * 8;
  const int x0 = (tb & 7) * 8;
  const int tid = threadIdx.x;

  if (tb == 0) {
    if (tid < 96) pool_sum[b * 96 + tid] = 0.f;
    else if (tid < 102) cnt[b * 6 + (tid - 96)] = 0.f;
  }

  const int lane = tid & 63;
  const int wv = tid >> 6;
  const int n = lane & 15;
  const int quad = lane >> 4;
  const int vy = n >> 2, vx = n & 3;

  // prebuilt weight A-fragments: 7 coalesced 16B loads (L2-resident 7KB)
  s16x8 wf[7];
  {
    const s16x8* wfp = (const s16x8*)(bpre + 4 * 7168);
#pragma unroll
    for (int i = 0; i < 7; ++i) wf[i] = wfp[i * 64 + lane];
  }

  for (int i = tid; i < 1728; i += 256) {
    const int row = i / 12;
    const int lx = i - row * 12;
    const int lz = row / 12;
    const int ly = row - lz * 12;
    const int gz = z0 + lz - 2, gy = y0 + ly - 2, gx = x0 + lx - 2;
    float v = 0.f;
    if ((unsigned)gz < 64u && (unsigned)gy < 64u && (unsigned)gx < 64u) {
      const int gi = ((b * 64 + gz) * 64 + gy) * 64 + gx;
      v = x[gi] * (float)mask[gi];
    }
    tl[row * 24 + lx] = (u16)bfrnd(v);
  }
  __syncthreads();

  if (tid < 144) {
    const uint4 a = *(const uint4*)&tl[tid * 24];
    const uint2 bq = *(const uint2*)&tl[tid * 24 + 8];
    u32 c[7];
    c[0] = a.x; c[1] = a.y; c[2] = a.z; c[3] = a.w;
    c[4] = bq.x; c[5] = bq.y; c[6] = 0u;
    u32 d[7];
#pragma unroll
    for (int k = 0; k < 6; ++k) d[k] = (c[k] >> 16) | (c[k + 1] << 16);
    d[6] = c[6] >> 16;
    uint4* dst = (uint4*)&cp[tid * 8];
    dst[0 * 146] = make_uint4(c[0], c[1], c[2], c[3]);
    dst[1 * 146] = make_uint4(d[0], d[1], d[2], d[3]);
    dst[2 * 146] = make_uint4(c[1], c[2], c[3], c[4]);
    dst[3 * 146] = make_uint4(d[1], d[2], d[3], d[4]);
    dst[4 * 146] = make_uint4(c[2], c[3], c[4], c[5]);
    dst[5 * 146] = make_uint4(d[2], d[3], d[4], d[5]);
    dst[6 * 146] = make_uint4(c[3], c[4], c[5], c[6]);
    dst[7 * 146] = make_uint4(d[3], d[4], d[5], d[6]);
  }
  __syncthreads();

  int doff[7];
#pragma unroll
  for (int i = 0; i < 7; ++i) {
    const int r = i * 4 + quad;
    doff[i] = (r < 25) ? ((r / 5) * 12 + (r % 5)) * 8 : 0;
  }

  for (int s = 0; s < 8; ++s) {
    const int sz = (s >> 2) * 4, sy = ((s >> 1) & 1) * 4, sx = (s & 1) * 4;
    const int base =
        (sx + vx) * 1168 + (((sz + wv) * 12) + (sy + vy)) * 8;
    f32x4 acc = {0.f, 0.f, 0.f, 0.f};
#pragma unroll
    for (int i = 0; i < 7; ++i) {
      const s16x8 bf = *(const s16x8*)&cp[base + doff[i]];
      acc = __builtin_amdgcn_mfma_f32_16x16x32_bf16(wf[i], bf, acc, 0, 0, 0);
    }
    const int Z = z0 + sz + wv, Y = y0 + sy + vy, X = x0 + sx + vx;
    const int gi = ((b * 64 + Z) * 64 + Y) * 64 + X;
    const float mv = (float)mask[gi];
    const float f0 = fmaxf(acc[0], 0.f) * mv;
    const float f1 = fmaxf(acc[1], 0.f) * mv;
    const float f2 = fmaxf(acc[2], 0.f) * mv;
    const float f3 = fmaxf(acc[3], 0.f) * mv;
    uint2* op = (uint2*)(yout + (size_t)gi * CH + quad * 4);
    op[0] = make_uint2(packbf(f0, f1), packbf(f2, f3));
  }
}

// ---- Stages 0..2: MFMA implicit GEMM, compile-time S (shifts not muls) ----
template <int S>
__global__ __launch_bounds__(256) void stage_mfma4(
    const u16* __restrict__ yin, const u16* __restrict__ bpre,
    const int* __restrict__ m_in_i, const float* __restrict__ m_in_f,
    u16* __restrict__ yout, float* __restrict__ m_out,
    float* __restrict__ pool_sum, float* __restrict__ cnt,
    const int stage)
{
  __shared__ u16 lb[14 * 512];
  __shared__ float lC[4 * 16 * 17];
  __shared__ float lmp[256];

  constexpr int So = S >> 1;
  constexpr int nvox = So * So * So;
  const int b = blockIdx.y;
  const int tid = threadIdx.x;
  const int vg0 = blockIdx.x * 256;

  {
    const uint4* src = (const uint4*)bpre;
    uint4* dst = (uint4*)lb;
    for (int e = tid; e < 896; e += 256) dst[e] = src[e];
  }

  {
    const int vox = vg0 + tid;
    const int oz = vox / (So * So);
    const int oy = (vox / So) % So;
    const int ox = vox % So;
    float mp = 0.f;
#pragma unroll
    for (int dz = 0; dz < 2; ++dz)
#pragma unroll
      for (int dy = 0; dy < 2; ++dy)
#pragma unroll
        for (int dx = 0; dx < 2; ++dx) {
          const int mi =
              ((b * S + 2 * oz + dz) * S + 2 * oy + dy) * S + 2 * ox + dx;
          const float mv = m_in_i ? (float)m_in_i[mi] : m_in_f[mi];
          mp = fmaxf(mp, mv);
        }
    lmp[tid] = mp;
  }
  __syncthreads();

  const int wv = tid >> 6;
  const int lane = tid & 63;
  const int m = lane & 15;
  const int quad = lane >> 4;
  const int qh = quad >> 1;
  const int qlo = quad & 1;

  int izb[4], iyb[4], ixb[4];
#pragma unroll
  for (int g = 0; g < 4; ++g) {
    const int vox = vg0 + wv * 64 + g * 16 + m;
    const int oz = vox / (So * So);
    const int oy = (vox / So) % So;
    const int ox = vox % So;
    izb[g] = 2 * oz - 1;
    iyb[g] = 2 * oy - 1;
    ixb[g] = 2 * ox - 1;
  }

  const s16x8* lbv = (const s16x8*)lb;
  f32x4 acc[4];
#pragma unroll
  for (int g = 0; g < 4; ++g) acc[g] = (f32x4){0.f, 0.f, 0.f, 0.f};

#pragma unroll
  for (int i = 0; i < 14; ++i) {
    const int t0 = 2 * i, t1 = 2 * i + 1;
    const int dz0 = t0 / 9, dy0 = (t0 / 3) % 3, dx0 = t0 % 3;
    const int dz1 = (t1 < 27) ? t1 / 9 : 1;
    const int dy1 = (t1 < 27) ? (t1 / 3) % 3 : 1;
    const int dx1 = (t1 < 27) ? t1 % 3 : 1;
    const int dzq = qh ? dz1 : dz0;
    const int dyq = qh ? dy1 : dy0;
    const int dxq = qh ? dx1 : dx0;

    uint4 ar[4];
#pragma unroll
    for (int g = 0; g < 4; ++g) {
      const int iz = izb[g] + dzq;
      const int iy = iyb[g] + dyq;
      const int ix = ixb[g] + dxq;
      const bool valid = (unsigned)iz < (unsigned)S &&
                         (unsigned)iy < (unsigned)S &&
                         (unsigned)ix < (unsigned)S;
      const int izc = min(max(iz, 0), S - 1);
      const int iyc = min(max(iy, 0), S - 1);
      const int ixc = min(max(ix, 0), S - 1);
      const size_t addr =
          (size_t)(((b * S + izc) * S + iyc) * S + ixc) * 16 + qlo * 8;
      uint4 v = *(const uint4*)(yin + addr);
      v.x = valid ? v.x : 0u;
      v.y = valid ? v.y : 0u;
      v.z = valid ? v.z : 0u;
      v.w = valid ? v.w : 0u;
      ar[g] = v;
    }
    const s16x8 bfrag = lbv[i * 64 + lane];
#pragma unroll
    for (int g = 0; g < 4; ++g)
      acc[g] = __builtin_amdgcn_mfma_f32_16x16x32_bf16(
          __builtin_bit_cast(s16x8, ar[g]), bfrag, acc[g], 0, 0, 0);
  }

  float psum = 0.f;
#pragma unroll
  for (int g = 0; g < 4; ++g) {
    __syncthreads();
    {
      float* lCw = lC + wv * 272;
      const int n = lane & 15;
#pragma unroll
      for (int reg = 0; reg < 4; ++reg) {
        const int row = quad * 4 + reg;
        lCw[row * 17 + n] =
            fmaxf(acc[g][reg], 0.f) * lmp[wv * 64 + g * 16 + row];
      }
    }
    __syncthreads();
    {
      const int vox_l = tid >> 2;
      const int cg = (tid & 3) * 4;
      const float* src = lC + (vox_l >> 4) * 272 + (vox_l & 15) * 17 + cg;
      const float f0 = src[0], f1 = src[1], f2 = src[2], f3 = src[3];
      const int lv = (vox_l >> 4) * 64 + g * 16 + (vox_l & 15);
      const size_t gi = (size_t)b * nvox + vg0 + lv;
      uint2* op = (uint2*)(yout + gi * 16 + cg);
      op[0] = make_uint2(packbf(f0, f1), packbf(f2, f3));
      if ((tid & 3) == 0) m_out[gi] = lmp[lv];
    }
    if (tid < 16) {
      float s = 0.f;
#pragma unroll 16
      for (int v = 0; v < 64; ++v)
        s += lC[(v >> 4) * 272 + (v & 15) * 17 + tid];
      psum += s;
    }
  }
  if (tid < 16) {
    atomicAdd(&pool_sum[(b * 6 + stage) * 16 + tid], psum);
  } else if (tid == 16) {
    float c = 0.f;
#pragma unroll 16
    for (int v = 0; v < 256; ++v) c += lmp[v];
    atomicAdd(&cnt[b * 6 + stage], c);
  }
}

// --------- Tail: stage 3 via MFMA (K split over 4 waves), stages 4/5 via
// split-K VALU, MLP head with parallel halves. One block per batch. ---------
__global__ __launch_bounds__(256) void tail_kernel(
    const u16* __restrict__ y3g, const float* __restrict__ m3g,
    const u16* __restrict__ bpre,
    const float* __restrict__ wstg,
    const float* __restrict__ meta, const float* __restrict__ sched,
    const float* __restrict__ mw1, const float* __restrict__ mb1,
    const float* __restrict__ mw2, const float* __restrict__ mb2,
    const float* __restrict__ matw, const float* __restrict__ matb,
    const float* __restrict__ schw, const float* __restrict__ schb,
    const float* __restrict__ f1w, const float* __restrict__ f1b,
    const float* __restrict__ f2w, const float* __restrict__ f2b,
    const float* __restrict__ pool_sum, const float* __restrict__ cnt,
    float* __restrict__ out)
{
  const int b = blockIdx.x;
  const int t = threadIdx.x;
  __shared__ u16 ty3[8192];           // y3 in bf16 (16 KB)
  __shared__ float lm3[512];
  __shared__ float pb[4 * 64 * 17];   // stage-3 wave partials (pad 17)
  __shared__ float ly4[64 * 16];
  __shared__ float lm4[64];
  __shared__ float ps4[256];
  __shared__ float ly5[8 * 16];
  __shared__ float lm5[8];
  __shared__ float ps5[128];
  __shared__ float lsum[3][16];
  __shared__ float lcnt[3];
  __shared__ float invec[112];
  __shared__ float hbuf[32];
  __shared__ float zbuf[256];
  __shared__ float psf[256];
  __shared__ float part[2];

  // ---- P0: load y3 (bf16) + m3
  {
    const uint4* yb = (const uint4*)(y3g + (size_t)b * 8192);
    uint4* dst = (uint4*)ty3;
    for (int i = t; i < 1024; i += 256) dst[i] = yb[i];
    for (int i = t; i < 512; i += 256) lm3[i] = m3g[b * 512 + i];
  }
  __syncthreads();

  // ---- P1: stage 3 MFMA, tap-pairs split across waves
  {
    const int lane = t & 63;
    const int wv = t >> 6;
    const int mm = lane & 15;
    const int quad = lane >> 4;
    const int qh = quad >> 1, qlo = quad & 1;

    int iz0[4], iy0[4], ix0[4];
#pragma unroll
    for (int g = 0; g < 4; ++g) {
      const int vox = g * 16 + mm;
      iz0[g] = 2 * (vox >> 4) - 1;
      iy0[g] = 2 * ((vox >> 2) & 3) - 1;
      ix0[g] = 2 * (vox & 3) - 1;
    }
    f32x4 a3[4];
#pragma unroll
    for (int g = 0; g < 4; ++g) a3[g] = (f32x4){0.f, 0.f, 0.f, 0.f};
    const s16x8* bp3 = (const s16x8*)(bpre + 3 * 7168);
#pragma unroll
    for (int ii = 0; ii < 4; ++ii) {
      const int i = wv * 4 + ii;
      if (i < 14) {
        const int t0 = 2 * i, t1 = 2 * i + 1;
        const int dz0 = t0 / 9, dy0 = (t0 / 3) % 3, dx0 = t0 % 3;
        const int dz1 = (t1 < 27) ? t1 / 9 : 1;
        const int dy1 = (t1 < 27) ? (t1 / 3) % 3 : 1;
        const int dx1 = (t1 < 27) ? t1 % 3 : 1;
        const int dzq = qh ? dz1 : dz0;
        const int dyq = qh ? dy1 : dy0;
        const int dxq = qh ? dx1 : dx0;
        uint4 ar[4];
#pragma unroll
        for (int g = 0; g < 4; ++g) {
          const int iz = iz0[g] + dzq;
          const int iy = iy0[g] + dyq;
          const int ix = ix0[g] + dxq;
          const bool valid = (unsigned)iz < 8u && (unsigned)iy < 8u &&
                             (unsigned)ix < 8u;
          const int izc = min(max(iz, 0), 7);
          const int iyc = min(max(iy, 0), 7);
          const int ixc = min(max(ix, 0), 7);
          const int ad = ((izc * 8 + iyc) * 8 + ixc) * 16 + qlo * 8;
          uint4 v = *(const uint4*)&ty3[ad];
          v.x = valid ? v.x : 0u;
          v.y = valid ? v.y : 0u;
          v.z = valid ? v.z : 0u;
          v.w = valid ? v.w : 0u;
          ar[g] = v;
        }
        const s16x8 bf = bp3[i * 64 + lane];
#pragma unroll
        for (int g = 0; g < 4; ++g)
          a3[g] = __builtin_amdgcn_mfma_f32_16x16x32_bf16(
              __builtin_bit_cast(s16x8, ar[g]), bf, a3[g], 0, 0, 0);
      }
    }
#pragma unroll
    for (int g = 0; g < 4; ++g)
#pragma unroll
      for (int reg = 0; reg < 4; ++reg)
        pb[wv * 1088 + (g * 16 + quad * 4 + reg) * 17 + mm] = a3[g][reg];
  }
  __syncthreads();

  // ---- P2: reduce 4 wave-partials -> relu * mask -> ly4 (f32)
  {
    const int vox = t >> 2, cg = (t & 3) * 4;
    const int oz = vox >> 4, oy = (vox >> 2) & 3, ox = vox & 3;
    float mp = 0.f;
#pragma unroll
    for (int dz = 0; dz < 2; ++dz)
#pragma unroll
      for (int dy = 0; dy < 2; ++dy)
#pragma unroll
        for (int dx = 0; dx < 2; ++dx)
          mp = fmaxf(mp, lm3[((2 * oz + dz) * 8 + 2 * oy + dy) * 8 +
                             2 * ox + dx]);
#pragma unroll
    for (int c = 0; c < 4; ++c) {
      const int ch = cg + c;
      const float s = pb[vox * 17 + ch] + pb[1088 + vox * 17 + ch] +
                      pb[2176 + vox * 17 + ch] + pb[3264 + vox * 17 + ch];
      ly4[vox * 16 + ch] = fmaxf(s, 0.f) * mp;
    }
    if (cg == 0) lm4[vox] = mp;
  }
  __syncthreads();

  // ---- P3: stage-3 pools + stage 4 split-K (all 256 threads)
  if (t < 16) {
    float s = 0.f;
#pragma unroll 16
    for (int v = 0; v < 64; ++v) s += ly4[v * 16 + t];
    lsum[0][t] = s;
  } else if (t == 16) {
    float s = 0.f;
#pragma unroll 16
    for (int v = 0; v < 64; ++v) s += lm4[v];
    lcnt[0] = s;
  }
  {
    const float* w = wstg + 4 * 27 * 256;
    const int o = t >> 1, kh = t & 1;
    const int vox4 = o >> 4, co = o & 15;
    const int oz = vox4 >> 2, oy = (vox4 >> 1) & 1, ox = vox4 & 1;
    float acc = 0.f;
#pragma unroll
    for (int tt = 0; tt < 14; ++tt) {
      const int tap = tt + (kh ? 14 : 0);
      if (tap < 27) {
        const int dz = tap / 9, dy = (tap / 3) % 3, dx = tap % 3;
        const int iz = 2 * oz + dz - 1, iy = 2 * oy + dy - 1,
                  ix = 2 * ox + dx - 1;
        const float s = ((unsigned)iz < 4u && (unsigned)iy < 4u &&
                         (unsigned)ix < 4u) ? 1.f : 0.f;
        const int idx = ((min(max(iz, 0), 3) * 4 + min(max(iy, 0), 3)) * 4 +
                         min(max(ix, 0), 3)) * 16;
        const float* wp = w + tap * 256 + co;
#pragma unroll
        for (int ci = 0; ci < 16; ++ci)
          acc = fmaf(ly4[idx + ci] * s, wp[ci * 16], acc);
      }
    }
    ps4[t] = acc;
  }
  __syncthreads();

  // ---- P4: combine stage-4 partials -> ly5
  if (t < 128) {
    const int vox4 = t >> 4, co = t & 15;
    float mp = 0.f;
#pragma unroll
    for (int dz = 0; dz < 2; ++dz)
#pragma unroll
      for (int dy = 0; dy < 2; ++dy)
#pragma unroll
        for (int dx = 0; dx < 2; ++dx)
          mp = fmaxf(mp, lm4[((2 * (vox4 >> 2) + dz) * 4 +
                              2 * ((vox4 >> 1) & 1) + dy) * 4 +
                             2 * (vox4 & 1) + dx]);
    ly5[t] = fmaxf(ps4[2 * t] + ps4[2 * t + 1], 0.f) * mp;
    if (co == 0) lm5[vox4] = mp;
  }
  __syncthreads();

  // ---- P5: stage-4 pools + stage 5 split-K (128 threads, 8 K-slices)
  if (t < 16) {
    float s = 0.f;
#pragma unroll
    for (int v = 0; v < 8; ++v) s += ly5[v * 16 + t];
    lsum[1][t] = s;
  } else if (t == 16) {
    lcnt[1] = lm5[0] + lm5[1] + lm5[2] + lm5[3] + lm5[4] + lm5[5] + lm5[6] +
              lm5[7];
  }
  if (t < 128) {
    const float* w = wstg + 5 * 27 * 256;
    const int co = t & 15, k8 = t >> 4;
    float acc = 0.f;
#pragma unroll
    for (int tt = 0; tt < 4; ++tt) {
      const int tap = k8 * 4 + tt;
      if (tap < 27) {
        const int dz = tap / 9, dy = (tap / 3) % 3, dx = tap % 3;
        const int iz = dz - 1, iy = dy - 1, ix = dx - 1;
        const float s = ((unsigned)iz < 2u && (unsigned)iy < 2u &&
                         (unsigned)ix < 2u) ? 1.f : 0.f;
        const int idx = ((min(max(iz, 0), 1) * 2 + min(max(iy, 0), 1)) * 2 +
                         min(max(ix, 0), 1)) * 16;
        const float* wp = w + tap * 256 + co;
#pragma unroll
        for (int ci = 0; ci < 16; ++ci)
          acc = fmaf(ly5[idx + ci] * s, wp[ci * 16], acc);
      }
    }
    ps5[t] = acc;
  }
  __syncthreads();

  // ---- P6: combine stage-5 partials; meta layer 1
  if (t < 16) {
    float s = ps5[t] + ps5[16 + t] + ps5[32 + t] + ps5[48 + t] +
              ps5[64 + t] + ps5[80 + t] + ps5[96 + t] + ps5[112 + t];
    float mp = 0.f;
#pragma unroll
    for (int v = 0; v < 8; ++v) mp = fmaxf(mp, lm5[v]);
    lsum[2][t] = fmaxf(s, 0.f) * mp;
    if (t == 0) lcnt[2] = mp;
  } else if (t >= 96 && t < 128) {
    const int j = t - 96;
    float h = mb1[j];
#pragma unroll
    for (int k = 0; k < 3; ++k) h = fmaf(meta[b * 3 + k], mw1[k * 32 + j], h);
    hbuf[j] = fmaxf(h, 0.f);
  }
  __syncthreads();

  // ---- P7: build invec (pools from global + local; meta_emb)
  if (t < 48) {
    const int s = t >> 4;
    invec[t] = pool_sum[b * 96 + t] / fmaxf(cnt[b * 6 + s], 1.f);
  } else if (t < 96) {
    const int s = (t >> 4) - 3;
    invec[t] = lsum[s][t & 15] / fmaxf(lcnt[s], 1.f);
  } else if (t < 112) {
    const int j = t - 96;
    float e = mb2[j];
#pragma unroll
    for (int k = 0; k < 32; ++k) e = fmaf(hbuf[k], mw2[k * 16 + j], e);
    invec[t] = e;  // no ReLU on meta_emb
  }
  __syncthreads();

  // ---- P8: zbuf = [relu(invec@matw), relu(sched@schw)] in parallel halves
  if (t < 128) {
    float a = matb[t];
#pragma unroll 16
    for (int k = 0; k < 112; ++k) a = fmaf(invec[k], matw[k * 128 + t], a);
    zbuf[t] = fmaxf(a, 0.f);
  } else {
    const int c = t - 128;
    float s = schb[c];
#pragma unroll 16
    for (int k = 0; k < 128; ++k)
      s = fmaf(sched[b * 128 + k], schw[k * 128 + c], s);
    zbuf[128 + c] = fmaxf(s, 0.f);
  }
  __syncthreads();

  // ---- P9: f1 with K split across thread halves
  {
    const int col = t & 127, kh = t >> 7;
    float a = 0.f;
#pragma unroll 16
    for (int kk = 0; kk < 128; ++kk) {
      const int k = kh * 128 + kk;
      a = fmaf(zbuf[k], f1w[k * 128 + col], a);
    }
    psf[t] = a;
  }
  __syncthreads();

  // ---- P10: final combine + dot with f2w
  if (t < 128) {
    const float a = psf[t] + psf[128 + t] + f1b[t];
    float v = fmaxf(a, 0.f) * f2w[t];
#pragma unroll
    for (int off = 32; off > 0; off >>= 1) v += __shfl_xor(v, off, 64);
    if ((t & 63) == 0) part[t >> 6] = v;
  }
  __syncthreads();
  if (t == 0) out[b] = part[0] + part[1] + f2b[0];
}

extern "C" void kernel_launch(void* const* d_in, const int* in_sizes, int n_in,
                              void* d_out, int out_size, void* d_ws,
                              size_t ws_size, hipStream_t stream)
{
  (void)in_sizes; (void)n_in; (void)out_size; (void)ws_size;
  const float* x      = (const float*)d_in[0];
  const int*   mask   = (const int*)  d_in[1];
  const float* meta   = (const float*)d_in[2];
  const float* sched  = (const float*)d_in[3];
  const float* w_stem = (const float*)d_in[4];
  const float* w_stg  = (const float*)d_in[5];
  const float* mw1    = (const float*)d_in[6];
  const float* mb1    = (const float*)d_in[7];
  const float* mw2    = (const float*)d_in[8];
  const float* mb2    = (const float*)d_in[9];
  const float* matw   = (const float*)d_in[10];
  const float* matb   = (const float*)d_in[11];
  const float* schw   = (const float*)d_in[12];
  const float* schb   = (const float*)d_in[13];
  const float* f1w    = (const float*)d_in[14];
  const float* f1b    = (const float*)d_in[15];
  const float* f2w    = (const float*)d_in[16];
  const float* f2b    = (const float*)d_in[17];
  float* out = (float*)d_out;

  char* ws = (char*)d_ws;
  size_t off = 0;
  auto alloc = [&](size_t nbytes) -> void* {
    void* p = ws + off;
    off += (nbytes + 255) & ~(size_t)255;
    return p;
  };

  u16* y0 = (u16*)alloc((size_t)NB * 64 * 64 * 64 * CH * 2);
  u16* y1 = (u16*)alloc((size_t)NB * 32 * 32 * 32 * CH * 2);
  u16* y2 = (u16*)alloc((size_t)NB * 16 * 16 * 16 * CH * 2);
  u16* y3 = (u16*)alloc((size_t)NB * 8 * 8 * 8 * CH * 2);
  float* m1 = (float*)alloc((size_t)NB * 32 * 32 * 32 * 4);
  float* m2 = (float*)alloc((size_t)NB * 16 * 16 * 16 * 4);
  float* m3 = (float*)alloc((size_t)NB * 8 * 8 * 8 * 4);
  float* pool_sum = (float*)alloc((NB * 96 + NB * 6) * 4);
  float* cnt = pool_sum + NB * 96;
  u16* bpre = (u16*)alloc((4 * 7168 + 3584) * 2);

  bprep_kernel<<<126, 256, 0, stream>>>(w_stg, w_stem, bpre);

  stem_mfma<<<dim3(512, NB), 256, 0, stream>>>(x, mask, bpre, y0,
                                               pool_sum, cnt);

  // stage 0: 64->32 (32768 vox / 256 = 128 blocks/batch)
  stage_mfma4<64><<<dim3(128, NB), 256, 0, stream>>>(
      y0, bpre + 0 * 7168, mask, (const float*)nullptr, y1, m1,
      pool_sum, cnt, 0);
  // stage 1: 32->16 (16 blocks/batch)
  stage_mfma4<32><<<dim3(16, NB), 256, 0, stream>>>(
      y1, bpre + 1 * 7168, (const int*)nullptr, m1, y2, m2,
      pool_sum, cnt, 1);
  // stage 2: 16->8 (2 blocks/batch)
  stage_mfma4<16><<<dim3(2, NB), 256, 0, stream>>>(
      y2, bpre + 2 * 7168, (const int*)nullptr, m2, y3, m3,
      pool_sum, cnt, 2);

  tail_kernel<<<NB, 256, 0, stream>>>(y3, m3, bpre, w_stg, meta, sched,
                                      mw1, mb1, mw2, mb2, matw, matb,
                                      schw, schb, f1w, f1b, f2w, f2b,
                                      pool_sum, cnt, out);
}

// Round 4
// 196.515 us; speedup vs baseline: 1.2466x; 1.0368x over previous
//
#include <hip/hip_runtime.h>

#define CH 16
#define NB 8

typedef unsigned short u16;
typedef unsigned int u32;
typedef __attribute__((ext_vector_type(8))) short s16x8;
typedef __attribute__((ext_vector_type(4))) float f32x4;

__device__ __forceinline__ float bflo(u32 u) { return __uint_as_float(u << 16); }
__device__ __forceinline__ float bfhi(u32 u) { return __uint_as_float(u & 0xffff0000u); }
__device__ __forceinline__ u32 bfrnd(float f) {
  u32 u = __float_as_uint(f);
  return (u + 0x7fffu + ((u >> 16) & 1u)) >> 16;
}
// HW packed f32->bf16 RNE convert: 1 VALU inst, bit-identical to bfrnd for
// finite inputs.
__device__ __forceinline__ u32 packbf_hw(float lo, float hi) {
  u32 r;
  asm("v_cvt_pk_bf16_f32 %0, %1, %2" : "=v"(r) : "v"(lo), "v"(hi));
  return r;
}

// ---- Prep: bf16 B-fragments for MFMA stages 0..3 + stem A-fragments -------
// bpre layout: [0 .. 4*7168)  : stage 0..3 B-fragments
//              [4*7168 .. +3584): stem weight fragments [i=0..6][lane][j=0..7]
__global__ __launch_bounds__(256) void bprep_kernel(
    const float* __restrict__ w_stg, const float* __restrict__ w_stem,
    u16* __restrict__ bpre)
{
  const int e = blockIdx.x * 256 + (int)threadIdx.x;
  if (e >= 4 * 7168 + 3584) return;
  if (e < 4 * 7168) {
    const int s = e / 7168, r0 = e % 7168;
    const int i = r0 >> 9;
    const int r = r0 & 511;
    const int l = r >> 3, j = r & 7;
    const int tap = 2 * i + (l >> 5);
    const int cin = ((l >> 4) & 1) * 8 + j;
    const int n = l & 15;
    const float* w = w_stg + s * 27 * 256;
    const float val = (tap < 27) ? w[(tap * 16 + cin) * 16 + n] : 0.f;
    bpre[s * 7168 + i * 512 + l * 8 + j] = (u16)bfrnd(val);
  } else {
    const int e2 = e - 4 * 7168;          // [i][lane][j]
    const int i = e2 >> 9;
    const int r0 = e2 & 511;
    const int lane = r0 >> 3, j = r0 & 7;
    const int quad = lane >> 4, n = lane & 15;
    const int r = i * 4 + quad;
    const float val = (r < 25 && j < 5) ? w_stem[(r * 5 + j) * 16 + n] : 0.f;
    bpre[4 * 7168 + e2] = (u16)bfrnd(val);
  }
}

// ---- Stem via MFMA implicit GEMM: merged row-load + copy-build ------------
// Thread r<144 loads its halo row (12 f32 x + 12 i32 mask) via float2/int2,
// converts with 12 v_cvt_pk, and writes the 8 shifted copies directly
// (no tl staging, one barrier). Main loop unchanged: 7 MFMA per subtile,
// conflict-free ds_read_b128 from shifted copies, prefetched epilogue mask.
__global__ __launch_bounds__(256, 6) void stem_mfma(
    const float* __restrict__ x, const int* __restrict__ mask,
    const u16* __restrict__ bpre, u16* __restrict__ yout,
    float* __restrict__ pool_sum, float* __restrict__ cnt)
{
  __shared__ u16 cp[8 * 1168];      // 8 shifted copies, stride 1168 u16

  const int b = blockIdx.y;
  const int u = blockIdx.x;
  const int tb = ((u & 7) << 6) | (u >> 3);   // XCD swizzle
  const int z0 = (tb >> 6) * 8;
  const int y0 = ((tb >> 3) & 7) * 8;
  const int x0 = (tb & 7) * 8;
  const int tid = threadIdx.x;

  if (tb == 0) {
    if (tid < 96) pool_sum[b * 96 + tid] = 0.f;
    else if (tid < 102) cnt[b * 6 + (tid - 96)] = 0.f;
  }

  const int lane = tid & 63;
  const int wv = tid >> 6;
  const int n = lane & 15;
  const int quad = lane >> 4;
  const int vy = n >> 2, vx = n & 3;

  // prebuilt weight A-fragments: 7 coalesced 16B loads (L2-resident 7KB)
  s16x8 wf[7];
  {
    const s16x8* wfp = (const s16x8*)(bpre + 4 * 7168);
#pragma unroll
    for (int i = 0; i < 7; ++i) wf[i] = wfp[i * 64 + lane];
  }

  // ---- merged load + shifted-copy build (144 row-threads) ----
  if (tid < 144) {
    const int lz = tid / 12, ly = tid - lz * 12;
    const int gz = z0 + lz - 2, gy = y0 + ly - 2;
    uint4* dst = (uint4*)&cp[tid * 8];
    if ((unsigned)gz < 64u && (unsigned)gy < 64u) {
      const long long rowg =
          ((long long)((b * 64 + gz) * 64 + gy)) * 64 + (x0 - 2);
      float v[12];
      if (rowg >= 0 && rowg + 12 <= (long long)NB * 64 * 64 * 64) {
        const float2* xp = (const float2*)(x + rowg);
        const int2* mp2 = (const int2*)(mask + rowg);
        float2 xv[6]; int2 mv2[6];
#pragma unroll
        for (int j = 0; j < 6; ++j) { xv[j] = xp[j]; mv2[j] = mp2[j]; }
#pragma unroll
        for (int j = 0; j < 6; ++j) {
          v[2 * j]     = xv[j].x * (float)mv2[j].x;
          v[2 * j + 1] = xv[j].y * (float)mv2[j].y;
        }
        if (x0 == 0)  { v[0] = 0.f;  v[1] = 0.f;  }
        if (x0 == 56) { v[10] = 0.f; v[11] = 0.f; }
      } else {
        // rare corner rows of the whole tensor: scalar clamped path
#pragma unroll
        for (int j = 0; j < 12; ++j) {
          const int gx = x0 - 2 + j;
          float vv = 0.f;
          if ((unsigned)gx < 64u) {
            const long long gi = rowg + j;
            vv = x[gi] * (float)mask[gi];
          }
          v[j] = vv;
        }
      }
      const u32 c0 = packbf_hw(v[0], v[1]);
      const u32 c1 = packbf_hw(v[2], v[3]);
      const u32 c2 = packbf_hw(v[4], v[5]);
      const u32 c3 = packbf_hw(v[6], v[7]);
      const u32 c4 = packbf_hw(v[8], v[9]);
      const u32 c5 = packbf_hw(v[10], v[11]);
      const u32 d0 = packbf_hw(v[1], v[2]);
      const u32 d1 = packbf_hw(v[3], v[4]);
      const u32 d2 = packbf_hw(v[5], v[6]);
      const u32 d3 = packbf_hw(v[7], v[8]);
      const u32 d4 = packbf_hw(v[9], v[10]);
      const u32 d5 = packbf_hw(v[11], 0.f);
      dst[0 * 146] = make_uint4(c0, c1, c2, c3);
      dst[1 * 146] = make_uint4(d0, d1, d2, d3);
      dst[2 * 146] = make_uint4(c1, c2, c3, c4);
      dst[3 * 146] = make_uint4(d1, d2, d3, d4);
      dst[4 * 146] = make_uint4(c2, c3, c4, c5);
      dst[5 * 146] = make_uint4(d2, d3, d4, d5);
      dst[6 * 146] = make_uint4(c3, c4, c5, 0u);
      dst[7 * 146] = make_uint4(d3, d4, d5, 0u);
    } else {
#pragma unroll
      for (int p = 0; p < 8; ++p) dst[p * 146] = make_uint4(0u, 0u, 0u, 0u);
    }
  }
  __syncthreads();

  // per-quad tap-row offsets (u16 units); r>=25 clamped to row 0 (zero wt)
  int doff[7];
#pragma unroll
  for (int i = 0; i < 7; ++i) {
    const int r = i * 4 + quad;
    doff[i] = (r < 25) ? ((r / 5) * 12 + (r % 5)) * 8 : 0;
  }
  const int base0 = vx * 1168 + (wv * 12 + vy) * 8;
  const int gi0 = ((b * 64 + z0 + wv) * 64 + y0 + vy) * 64 + x0 + vx;
  u16* outp = yout + (size_t)gi0 * 16 + quad * 4;

  float mvc = (float)mask[gi0];       // subtile-0 mask, issued early
  for (int s = 0; s < 8; ++s) {
    const int sz = (s >> 2) * 4, sy2 = ((s >> 1) & 1) * 4, sx = (s & 1) * 4;
    const int off = sz * 4096 + sy2 * 64 + sx;
    float mvn = 0.f;
    if (s < 7) {                      // prefetch next subtile's mask
      const int s1 = s + 1;
      const int offn = ((s1 >> 2) * 4) * 4096 + (((s1 >> 1) & 1) * 4) * 64 +
                       (s1 & 1) * 4;
      mvn = (float)mask[gi0 + offn];
    }
    const int base = base0 + sx * 1168 + (sz * 12 + sy2) * 8;
    f32x4 acc = {0.f, 0.f, 0.f, 0.f};
#pragma unroll
    for (int i = 0; i < 7; ++i) {
      const s16x8 bf = *(const s16x8*)&cp[base + doff[i]];
      acc = __builtin_amdgcn_mfma_f32_16x16x32_bf16(wf[i], bf, acc, 0, 0, 0);
    }
    const float f0 = fmaxf(acc[0], 0.f) * mvc;
    const float f1 = fmaxf(acc[1], 0.f) * mvc;
    const float f2 = fmaxf(acc[2], 0.f) * mvc;
    const float f3 = fmaxf(acc[3], 0.f) * mvc;
    *(uint2*)(outp + (size_t)off * 16) =
        make_uint2(packbf_hw(f0, f1), packbf_hw(f2, f3));
    mvc = mvn;
  }
}

// ---- Stages 0..2: MFMA implicit GEMM, compile-time S (shifts not muls) ----
template <int S>
__global__ __launch_bounds__(256) void stage_mfma4(
    const u16* __restrict__ yin, const u16* __restrict__ bpre,
    const int* __restrict__ m_in_i, const float* __restrict__ m_in_f,
    u16* __restrict__ yout, float* __restrict__ m_out,
    float* __restrict__ pool_sum, float* __restrict__ cnt,
    const int stage)
{
  __shared__ u16 lb[14 * 512];
  __shared__ float lC[4 * 16 * 17];
  __shared__ float lmp[256];

  constexpr int So = S >> 1;
  constexpr int nvox = So * So * So;
  const int b = blockIdx.y;
  const int tid = threadIdx.x;
  const int vg0 = blockIdx.x * 256;

  {
    const uint4* src = (const uint4*)bpre;
    uint4* dst = (uint4*)lb;
    for (int e = tid; e < 896; e += 256) dst[e] = src[e];
  }

  {
    const int vox = vg0 + tid;
    const int oz = vox / (So * So);
    const int oy = (vox / So) % So;
    const int ox = vox % So;
    float mp = 0.f;
#pragma unroll
    for (int dz = 0; dz < 2; ++dz)
#pragma unroll
      for (int dy = 0; dy < 2; ++dy)
#pragma unroll
        for (int dx = 0; dx < 2; ++dx) {
          const int mi =
              ((b * S + 2 * oz + dz) * S + 2 * oy + dy) * S + 2 * ox + dx;
          const float mv = m_in_i ? (float)m_in_i[mi] : m_in_f[mi];
          mp = fmaxf(mp, mv);
        }
    lmp[tid] = mp;
  }
  __syncthreads();

  const int wv = tid >> 6;
  const int lane = tid & 63;
  const int m = lane & 15;
  const int quad = lane >> 4;
  const int qh = quad >> 1;
  const int qlo = quad & 1;

  int izb[4], iyb[4], ixb[4];
#pragma unroll
  for (int g = 0; g < 4; ++g) {
    const int vox = vg0 + wv * 64 + g * 16 + m;
    const int oz = vox / (So * So);
    const int oy = (vox / So) % So;
    const int ox = vox % So;
    izb[g] = 2 * oz - 1;
    iyb[g] = 2 * oy - 1;
    ixb[g] = 2 * ox - 1;
  }

  const s16x8* lbv = (const s16x8*)lb;
  f32x4 acc[4];
#pragma unroll
  for (int g = 0; g < 4; ++g) acc[g] = (f32x4){0.f, 0.f, 0.f, 0.f};

#pragma unroll
  for (int i = 0; i < 14; ++i) {
    const int t0 = 2 * i, t1 = 2 * i + 1;
    const int dz0 = t0 / 9, dy0 = (t0 / 3) % 3, dx0 = t0 % 3;
    const int dz1 = (t1 < 27) ? t1 / 9 : 1;
    const int dy1 = (t1 < 27) ? (t1 / 3) % 3 : 1;
    const int dx1 = (t1 < 27) ? t1 % 3 : 1;
    const int dzq = qh ? dz1 : dz0;
    const int dyq = qh ? dy1 : dy0;
    const int dxq = qh ? dx1 : dx0;

    uint4 ar[4];
#pragma unroll
    for (int g = 0; g < 4; ++g) {
      const int iz = izb[g] + dzq;
      const int iy = iyb[g] + dyq;
      const int ix = ixb[g] + dxq;
      const bool valid = (unsigned)iz < (unsigned)S &&
                         (unsigned)iy < (unsigned)S &&
                         (unsigned)ix < (unsigned)S;
      const int izc = min(max(iz, 0), S - 1);
      const int iyc = min(max(iy, 0), S - 1);
      const int ixc = min(max(ix, 0), S - 1);
      const size_t addr =
          (size_t)(((b * S + izc) * S + iyc) * S + ixc) * 16 + qlo * 8;
      uint4 v = *(const uint4*)(yin + addr);
      v.x = valid ? v.x : 0u;
      v.y = valid ? v.y : 0u;
      v.z = valid ? v.z : 0u;
      v.w = valid ? v.w : 0u;
      ar[g] = v;
    }
    const s16x8 bfrag = lbv[i * 64 + lane];
#pragma unroll
    for (int g = 0; g < 4; ++g)
      acc[g] = __builtin_amdgcn_mfma_f32_16x16x32_bf16(
          __builtin_bit_cast(s16x8, ar[g]), bfrag, acc[g], 0, 0, 0);
  }

  float psum = 0.f;
#pragma unroll
  for (int g = 0; g < 4; ++g) {
    __syncthreads();
    {
      float* lCw = lC + wv * 272;
      const int n = lane & 15;
#pragma unroll
      for (int reg = 0; reg < 4; ++reg) {
        const int row = quad * 4 + reg;
        lCw[row * 17 + n] =
            fmaxf(acc[g][reg], 0.f) * lmp[wv * 64 + g * 16 + row];
      }
    }
    __syncthreads();
    {
      const int vox_l = tid >> 2;
      const int cg = (tid & 3) * 4;
      const float* src = lC + (vox_l >> 4) * 272 + (vox_l & 15) * 17 + cg;
      const float f0 = src[0], f1 = src[1], f2 = src[2], f3 = src[3];
      const int lv = (vox_l >> 4) * 64 + g * 16 + (vox_l & 15);
      const size_t gi = (size_t)b * nvox + vg0 + lv;
      uint2* op = (uint2*)(yout + gi * 16 + cg);
      op[0] = make_uint2(packbf_hw(f0, f1), packbf_hw(f2, f3));
      if ((tid & 3) == 0) m_out[gi] = lmp[lv];
    }
    if (tid < 16) {
      float s = 0.f;
#pragma unroll 16
      for (int v = 0; v < 64; ++v)
        s += lC[(v >> 4) * 272 + (v & 15) * 17 + tid];
      psum += s;
    }
  }
  if (tid < 16) {
    atomicAdd(&pool_sum[(b * 6 + stage) * 16 + tid], psum);
  } else if (tid == 16) {
    float c = 0.f;
#pragma unroll 16
    for (int v = 0; v < 256; ++v) c += lmp[v];
    atomicAdd(&cnt[b * 6 + stage], c);
  }
}

// --------- Tail: stage 3 via MFMA (K split over 4 waves), stages 4/5 via
// split-K VALU, MLP head with parallel halves. One block per batch. ---------
__global__ __launch_bounds__(256) void tail_kernel(
    const u16* __restrict__ y3g, const float* __restrict__ m3g,
    const u16* __restrict__ bpre,
    const float* __restrict__ wstg,
    const float* __restrict__ meta, const float* __restrict__ sched,
    const float* __restrict__ mw1, const float* __restrict__ mb1,
    const float* __restrict__ mw2, const float* __restrict__ mb2,
    const float* __restrict__ matw, const float* __restrict__ matb,
    const float* __restrict__ schw, const float* __restrict__ schb,
    const float* __restrict__ f1w, const float* __restrict__ f1b,
    const float* __restrict__ f2w, const float* __restrict__ f2b,
    const float* __restrict__ pool_sum, const float* __restrict__ cnt,
    float* __restrict__ out)
{
  const int b = blockIdx.x;
  const int t = threadIdx.x;
  __shared__ u16 ty3[8192];           // y3 in bf16 (16 KB)
  __shared__ float lm3[512];
  __shared__ float pb[4 * 64 * 17];   // stage-3 wave partials (pad 17)
  __shared__ float ly4[64 * 16];
  __shared__ float lm4[64];
  __shared__ float ps4[256];
  __shared__ float ly5[8 * 16];
  __shared__ float lm5[8];
  __shared__ float ps5[128];
  __shared__ float lsum[3][16];
  __shared__ float lcnt[3];
  __shared__ float invec[112];
  __shared__ float hbuf[32];
  __shared__ float zbuf[256];
  __shared__ float psf[256];
  __shared__ float part[2];

  // ---- P0: load y3 (bf16) + m3
  {
    const uint4* yb = (const uint4*)(y3g + (size_t)b * 8192);
    uint4* dst = (uint4*)ty3;
    for (int i = t; i < 1024; i += 256) dst[i] = yb[i];
    for (int i = t; i < 512; i += 256) lm3[i] = m3g[b * 512 + i];
  }
  __syncthreads();

  // ---- P1: stage 3 MFMA, tap-pairs split across waves
  {
    const int lane = t & 63;
    const int wv = t >> 6;
    const int mm = lane & 15;
    const int quad = lane >> 4;
    const int qh = quad >> 1, qlo = quad & 1;

    int iz0[4], iy0[4], ix0[4];
#pragma unroll
    for (int g = 0; g < 4; ++g) {
      const int vox = g * 16 + mm;
      iz0[g] = 2 * (vox >> 4) - 1;
      iy0[g] = 2 * ((vox >> 2) & 3) - 1;
      ix0[g] = 2 * (vox & 3) - 1;
    }
    f32x4 a3[4];
#pragma unroll
    for (int g = 0; g < 4; ++g) a3[g] = (f32x4){0.f, 0.f, 0.f, 0.f};
    const s16x8* bp3 = (const s16x8*)(bpre + 3 * 7168);
#pragma unroll
    for (int ii = 0; ii < 4; ++ii) {
      const int i = wv * 4 + ii;
      if (i < 14) {
        const int t0 = 2 * i, t1 = 2 * i + 1;
        const int dz0 = t0 / 9, dy0 = (t0 / 3) % 3, dx0 = t0 % 3;
        const int dz1 = (t1 < 27) ? t1 / 9 : 1;
        const int dy1 = (t1 < 27) ? (t1 / 3) % 3 : 1;
        const int dx1 = (t1 < 27) ? t1 % 3 : 1;
        const int dzq = qh ? dz1 : dz0;
        const int dyq = qh ? dy1 : dy0;
        const int dxq = qh ? dx1 : dx0;
        uint4 ar[4];
#pragma unroll
        for (int g = 0; g < 4; ++g) {
          const int iz = iz0[g] + dzq;
          const int iy = iy0[g] + dyq;
          const int ix = ix0[g] + dxq;
          const bool valid = (unsigned)iz < 8u && (unsigned)iy < 8u &&
                             (unsigned)ix < 8u;
          const int izc = min(max(iz, 0), 7);
          const int iyc = min(max(iy, 0), 7);
          const int ixc = min(max(ix, 0), 7);
          const int ad = ((izc * 8 + iyc) * 8 + ixc) * 16 + qlo * 8;
          uint4 v = *(const uint4*)&ty3[ad];
          v.x = valid ? v.x : 0u;
          v.y = valid ? v.y : 0u;
          v.z = valid ? v.z : 0u;
          v.w = valid ? v.w : 0u;
          ar[g] = v;
        }
        const s16x8 bf = bp3[i * 64 + lane];
#pragma unroll
        for (int g = 0; g < 4; ++g)
          a3[g] = __builtin_amdgcn_mfma_f32_16x16x32_bf16(
              __builtin_bit_cast(s16x8, ar[g]), bf, a3[g], 0, 0, 0);
      }
    }
#pragma unroll
    for (int g = 0; g < 4; ++g)
#pragma unroll
      for (int reg = 0; reg < 4; ++reg)
        pb[wv * 1088 + (g * 16 + quad * 4 + reg) * 17 + mm] = a3[g][reg];
  }
  __syncthreads();

  // ---- P2: reduce 4 wave-partials -> relu * mask -> ly4 (f32)
  {
    const int vox = t >> 2, cg = (t & 3) * 4;
    const int oz = vox >> 4, oy = (vox >> 2) & 3, ox = vox & 3;
    float mp = 0.f;
#pragma unroll
    for (int dz = 0; dz < 2; ++dz)
#pragma unroll
      for (int dy = 0; dy < 2; ++dy)
#pragma unroll
        for (int dx = 0; dx < 2; ++dx)
          mp = fmaxf(mp, lm3[((2 * oz + dz) * 8 + 2 * oy + dy) * 8 +
                             2 * ox + dx]);
#pragma unroll
    for (int c = 0; c < 4; ++c) {
      const int ch = cg + c;
      const float s = pb[vox * 17 + ch] + pb[1088 + vox * 17 + ch] +
                      pb[2176 + vox * 17 + ch] + pb[3264 + vox * 17 + ch];
      ly4[vox * 16 + ch] = fmaxf(s, 0.f) * mp;
    }
    if (cg == 0) lm4[vox] = mp;
  }
  __syncthreads();

  // ---- P3: stage-3 pools + stage 4 split-K (all 256 threads)
  if (t < 16) {
    float s = 0.f;
#pragma unroll 16
    for (int v = 0; v < 64; ++v) s += ly4[v * 16 + t];
    lsum[0][t] = s;
  } else if (t == 16) {
    float s = 0.f;
#pragma unroll 16
    for (int v = 0; v < 64; ++v) s += lm4[v];
    lcnt[0] = s;
  }
  {
    const float* w = wstg + 4 * 27 * 256;
    const int o = t >> 1, kh = t & 1;
    const int vox4 = o >> 4, co = o & 15;
    const int oz = vox4 >> 2, oy = (vox4 >> 1) & 1, ox = vox4 & 1;
    float acc = 0.f;
#pragma unroll
    for (int tt = 0; tt < 14; ++tt) {
      const int tap = tt + (kh ? 14 : 0);
      if (tap < 27) {
        const int dz = tap / 9, dy = (tap / 3) % 3, dx = tap % 3;
        const int iz = 2 * oz + dz - 1, iy = 2 * oy + dy - 1,
                  ix = 2 * ox + dx - 1;
        const float s = ((unsigned)iz < 4u && (unsigned)iy < 4u &&
                         (unsigned)ix < 4u) ? 1.f : 0.f;
        const int idx = ((min(max(iz, 0), 3) * 4 + min(max(iy, 0), 3)) * 4 +
                         min(max(ix, 0), 3)) * 16;
        const float* wp = w + tap * 256 + co;
#pragma unroll
        for (int ci = 0; ci < 16; ++ci)
          acc = fmaf(ly4[idx + ci] * s, wp[ci * 16], acc);
      }
    }
    ps4[t] = acc;
  }
  __syncthreads();

  // ---- P4: combine stage-4 partials -> ly5
  if (t < 128) {
    const int vox4 = t >> 4, co = t & 15;
    float mp = 0.f;
#pragma unroll
    for (int dz = 0; dz < 2; ++dz)
#pragma unroll
      for (int dy = 0; dy < 2; ++dy)
#pragma unroll
        for (int dx = 0; dx < 2; ++dx)
          mp = fmaxf(mp, lm4[((2 * (vox4 >> 2) + dz) * 4 +
                              2 * ((vox4 >> 1) & 1) + dy) * 4 +
                             2 * (vox4 & 1) + dx]);
    ly5[t] = fmaxf(ps4[2 * t] + ps4[2 * t + 1], 0.f) * mp;
    if (co == 0) lm5[vox4] = mp;
  }
  __syncthreads();

  // ---- P5: stage-4 pools + stage 5 split-K (128 threads, 8 K-slices)
  if (t < 16) {
    float s = 0.f;
#pragma unroll
    for (int v = 0; v < 8; ++v) s += ly5[v * 16 + t];
    lsum[1][t] = s;
  } else if (t == 16) {
    lcnt[1] = lm5[0] + lm5[1] + lm5[2] + lm5[3] + lm5[4] + lm5[5] + lm5[6] +
              lm5[7];
  }
  if (t < 128) {
    const float* w = wstg + 5 * 27 * 256;
    const int co = t & 15, k8 = t >> 4;
    float acc = 0.f;
#pragma unroll
    for (int tt = 0; tt < 4; ++tt) {
      const int tap = k8 * 4 + tt;
      if (tap < 27) {
        const int dz = tap / 9, dy = (tap / 3) % 3, dx = tap % 3;
        const int iz = dz - 1, iy = dy - 1, ix = dx - 1;
        const float s = ((unsigned)iz < 2u && (unsigned)iy < 2u &&
                         (unsigned)ix < 2u) ? 1.f : 0.f;
        const int idx = ((min(max(iz, 0), 1) * 2 + min(max(iy, 0), 1)) * 2 +
                         min(max(ix, 0), 1)) * 16;
        const float* wp = w + tap * 256 + co;
#pragma unroll
        for (int ci = 0; ci < 16; ++ci)
          acc = fmaf(ly5[idx + ci] * s, wp[ci * 16], acc);
      }
    }
    ps5[t] = acc;
  }
  __syncthreads();

  // ---- P6: combine stage-5 partials; meta layer 1
  if (t < 16) {
    float s = ps5[t] + ps5[16 + t] + ps5[32 + t] + ps5[48 + t] +
              ps5[64 + t] + ps5[80 + t] + ps5[96 + t] + ps5[112 + t];
    float mp = 0.f;
#pragma unroll
    for (int v = 0; v < 8; ++v) mp = fmaxf(mp, lm5[v]);
    lsum[2][t] = fmaxf(s, 0.f) * mp;
    if (t == 0) lcnt[2] = mp;
  } else if (t >= 96 && t < 128) {
    const int j = t - 96;
    float h = mb1[j];
#pragma unroll
    for (int k = 0; k < 3; ++k) h = fmaf(meta[b * 3 + k], mw1[k * 32 + j], h);
    hbuf[j] = fmaxf(h, 0.f);
  }
  __syncthreads();

  // ---- P7: build invec (pools from global + local; meta_emb)
  if (t < 48) {
    const int s = t >> 4;
    invec[t] = pool_sum[b * 96 + t] / fmaxf(cnt[b * 6 + s], 1.f);
  } else if (t < 96) {
    const int s = (t >> 4) - 3;
    invec[t] = lsum[s][t & 15] / fmaxf(lcnt[s], 1.f);
  } else if (t < 112) {
    const int j = t - 96;
    float e = mb2[j];
#pragma unroll
    for (int k = 0; k < 32; ++k) e = fmaf(hbuf[k], mw2[k * 16 + j], e);
    invec[t] = e;  // no ReLU on meta_emb
  }
  __syncthreads();

  // ---- P8: zbuf = [relu(invec@matw), relu(sched@schw)] in parallel halves
  if (t < 128) {
    float a = matb[t];
#pragma unroll 16
    for (int k = 0; k < 112; ++k) a = fmaf(invec[k], matw[k * 128 + t], a);
    zbuf[t] = fmaxf(a, 0.f);
  } else {
    const int c = t - 128;
    float s = schb[c];
#pragma unroll 16
    for (int k = 0; k < 128; ++k)
      s = fmaf(sched[b * 128 + k], schw[k * 128 + c], s);
    zbuf[128 + c] = fmaxf(s, 0.f);
  }
  __syncthreads();

  // ---- P9: f1 with K split across thread halves
  {
    const int col = t & 127, kh = t >> 7;
    float a = 0.f;
#pragma unroll 16
    for (int kk = 0; kk < 128; ++kk) {
      const int k = kh * 128 + kk;
      a = fmaf(zbuf[k], f1w[k * 128 + col], a);
    }
    psf[t] = a;
  }
  __syncthreads();

  // ---- P10: final combine + dot with f2w
  if (t < 128) {
    const float a = psf[t] + psf[128 + t] + f1b[t];
    float v = fmaxf(a, 0.f) * f2w[t];
#pragma unroll
    for (int off = 32; off > 0; off >>= 1) v += __shfl_xor(v, off, 64);
    if ((t & 63) == 0) part[t >> 6] = v;
  }
  __syncthreads();
  if (t == 0) out[b] = part[0] + part[1] + f2b[0];
}

extern "C" void kernel_launch(void* const* d_in, const int* in_sizes, int n_in,
                              void* d_out, int out_size, void* d_ws,
                              size_t ws_size, hipStream_t stream)
{
  (void)in_sizes; (void)n_in; (void)out_size; (void)ws_size;
  const float* x      = (const float*)d_in[0];
  const int*   mask   = (const int*)  d_in[1];
  const float* meta   = (const float*)d_in[2];
  const float* sched  = (const float*)d_in[3];
  const float* w_stem = (const float*)d_in[4];
  const float* w_stg  = (const float*)d_in[5];
  const float* mw1    = (const float*)d_in[6];
  const float* mb1    = (const float*)d_in[7];
  const float* mw2    = (const float*)d_in[8];
  const float* mb2    = (const float*)d_in[9];
  const float* matw   = (const float*)d_in[10];
  const float* matb   = (const float*)d_in[11];
  const float* schw   = (const float*)d_in[12];
  const float* schb   = (const float*)d_in[13];
  const float* f1w    = (const float*)d_in[14];
  const float* f1b    = (const float*)d_in[15];
  const float* f2w    = (const float*)d_in[16];
  const float* f2b    = (const float*)d_in[17];
  float* out = (float*)d_out;

  char* ws = (char*)d_ws;
  size_t off = 0;
  auto alloc = [&](size_t nbytes) -> void* {
    void* p = ws + off;
    off += (nbytes + 255) & ~(size_t)255;
    return p;
  };

  u16* y0 = (u16*)alloc((size_t)NB * 64 * 64 * 64 * CH * 2);
  u16* y1 = (u16*)alloc((size_t)NB * 32 * 32 * 32 * CH * 2);
  u16* y2 = (u16*)alloc((size_t)NB * 16 * 16 * 16 * CH * 2);
  u16* y3 = (u16*)alloc((size_t)NB * 8 * 8 * 8 * CH * 2);
  float* m1 = (float*)alloc((size_t)NB * 32 * 32 * 32 * 4);
  float* m2 = (float*)alloc((size_t)NB * 16 * 16 * 16 * 4);
  float* m3 = (float*)alloc((size_t)NB * 8 * 8 * 8 * 4);
  float* pool_sum = (float*)alloc((NB * 96 + NB * 6) * 4);
  float* cnt = pool_sum + NB * 96;
  u16* bpre = (u16*)alloc((4 * 7168 + 3584) * 2);

  bprep_kernel<<<126, 256, 0, stream>>>(w_stg, w_stem, bpre);

  stem_mfma<<<dim3(512, NB), 256, 0, stream>>>(x, mask, bpre, y0,
                                               pool_sum, cnt);

  // stage 0: 64->32 (32768 vox / 256 = 128 blocks/batch)
  stage_mfma4<64><<<dim3(128, NB), 256, 0, stream>>>(
      y0, bpre + 0 * 7168, mask, (const float*)nullptr, y1, m1,
      pool_sum, cnt, 0);
  // stage 1: 32->16 (16 blocks/batch)
  stage_mfma4<32><<<dim3(16, NB), 256, 0, stream>>>(
      y1, bpre + 1 * 7168, (const int*)nullptr, m1, y2, m2,
      pool_sum, cnt, 1);
  // stage 2: 16->8 (2 blocks/batch)
  stage_mfma4<16><<<dim3(2, NB), 256, 0, stream>>>(
      y2, bpre + 2 * 7168, (const int*)nullptr, m2, y3, m3,
      pool_sum, cnt, 2);

  tail_kernel<<<NB, 256, 0, stream>>>(y3, m3, bpre, w_stg, meta, sched,
                                      mw1, mb1, mw2, mb2, matw, matb,
                                      schw, schb, f1w, f1b, f2w, f2b,
                                      pool_sum, cnt, out);
}